// Round 5
// baseline (1415.463 us; speedup 1.0000x reference)
//
#include <hip/hip_runtime.h>
#include <cstdint>

#define NN 4096
#define EE 131072
#define BB 64
#define EPAD (EE + 8 * NN)   // CSR rows padded to multiples of 8

typedef float f4 __attribute__((ext_vector_type(4)));

// ---------------------------------------------------------------------------
// Graph preprocessing
// ---------------------------------------------------------------------------
__global__ void k_deg_hist(const int* __restrict__ src, const int* __restrict__ dst,
                           const float* __restrict__ ew, float* __restrict__ deg,
                           int* __restrict__ cnt) {
    int e = blockIdx.x * blockDim.x + threadIdx.x;
    if (e >= EE) return;
    atomicAdd(&deg[src[e]], ew[e]);
    atomicAdd(&cnt[dst[e]], 1);
}

// scan of per-row counts PADDED to multiples of 8 -> uniform, tail-free SpMM loops
__global__ __launch_bounds__(1024) void k_scan(const int* __restrict__ cnt,
                                               int* __restrict__ rowptr,
                                               int* __restrict__ cursor) {
    __shared__ int s[1024];
    int tid = threadIdx.x;
    int p0 = (cnt[tid * 4 + 0] + 7) & ~7;
    int p1 = (cnt[tid * 4 + 1] + 7) & ~7;
    int p2 = (cnt[tid * 4 + 2] + 7) & ~7;
    int p3 = (cnt[tid * 4 + 3] + 7) & ~7;
    int sum = p0 + p1 + p2 + p3;
    s[tid] = sum;
    __syncthreads();
    for (int off = 1; off < 1024; off <<= 1) {
        int t = (tid >= off) ? s[tid - off] : 0;
        __syncthreads();
        s[tid] += t;
        __syncthreads();
    }
    int excl = s[tid] - sum;
    rowptr[tid * 4 + 0] = excl; cursor[tid * 4 + 0] = excl; excl += p0;
    rowptr[tid * 4 + 1] = excl; cursor[tid * 4 + 1] = excl; excl += p1;
    rowptr[tid * 4 + 2] = excl; cursor[tid * 4 + 2] = excl; excl += p2;
    rowptr[tid * 4 + 3] = excl; cursor[tid * 4 + 3] = excl; excl += p3;
    if (tid == 1023) rowptr[4096] = excl;
}

// cv[pos] = (col, val_bits); pad slots stay {0, 0.0f} from the memset
__global__ void k_fill(const int* __restrict__ src, const int* __restrict__ dst,
                       const float* __restrict__ ew, const float* __restrict__ deg,
                       int* __restrict__ cursor, int2* __restrict__ cv) {
    int e = blockIdx.x * blockDim.x + threadIdx.x;
    if (e >= EE) return;
    int s = src[e], d = dst[e];
    int pos = atomicAdd(&cursor[d], 1);
    float ds = deg[s], dd = deg[d];
    float is = ds > 0.f ? rsqrtf(fmaxf(ds, 1e-30f)) : 0.f;
    float id = dd > 0.f ? rsqrtf(fmaxf(dd, 1e-30f)) : 0.f;
    float v = -(is * ew[e] * id);
    cv[pos] = make_int2(s, __float_as_int(v));
}

// ---------------------------------------------------------------------------
// Transpose x [B,N] -> X0 [N,B]
// ---------------------------------------------------------------------------
__global__ __launch_bounds__(256) void k_transpose_x(const float* __restrict__ x,
                                                     float* __restrict__ X0) {
    __shared__ float s[64 * 65];
    int n0 = blockIdx.x * 64;
    for (int idx = threadIdx.x; idx < 4096; idx += 256) {
        int b = idx >> 6, nl = idx & 63;
        s[nl * 65 + b] = x[(size_t)b * NN + n0 + nl];
    }
    __syncthreads();
    for (int idx = threadIdx.x; idx < 4096; idx += 256) {
        int nl = idx >> 6, b = idx & 63;
        X0[(size_t)(n0 + nl) * 64 + b] = s[nl * 65 + b];
    }
}

// ---------------------------------------------------------------------------
// SpMM narrow (width 64, layer 1), tail-free x8 gather loop
// ---------------------------------------------------------------------------
__global__ __launch_bounds__(64) void k_spmm_narrow(const int* __restrict__ rowptr,
                                                    const int2* __restrict__ cv,
                                                    const float* __restrict__ Zin,
                                                    const float* __restrict__ Tprev,
                                                    float* __restrict__ Tout,
                                                    float alpha, int useprev) {
    int n = blockIdx.x;
    int lane = threadIdx.x;
    int start = rowptr[n], end = rowptr[n + 1];
    float acc = 0.f;
    for (int e = start; e < end; e += 8) {
        const int4* q = reinterpret_cast<const int4*>(cv + e);  // 16B aligned
        int4 a = q[0], b = q[1], c = q[2], d = q[3];
        float z0 = Zin[((size_t)a.x << 6) + lane];
        float z1 = Zin[((size_t)a.z << 6) + lane];
        float z2 = Zin[((size_t)b.x << 6) + lane];
        float z3 = Zin[((size_t)b.z << 6) + lane];
        float z4 = Zin[((size_t)c.x << 6) + lane];
        float z5 = Zin[((size_t)c.z << 6) + lane];
        float z6 = Zin[((size_t)d.x << 6) + lane];
        float z7 = Zin[((size_t)d.z << 6) + lane];
        acc += __int_as_float(a.y) * z0 + __int_as_float(a.w) * z1
             + __int_as_float(b.y) * z2 + __int_as_float(b.w) * z3
             + __int_as_float(c.y) * z4 + __int_as_float(c.w) * z5
             + __int_as_float(d.y) * z6 + __int_as_float(d.w) * z7;
    }
    size_t o = ((size_t)n << 6) + lane;
    float r = alpha * acc;
    if (useprev) r -= Tprev[o];
    Tout[o] = r;
}

// ---------------------------------------------------------------------------
// Layer-1 expand: H[n, b*32+co] = relu( sum_k Tk[n,b] * w1[k,co] + b1[co] )
// Narrow inputs (4 x [N][64]); one 32MB write, no rmw.
// ---------------------------------------------------------------------------
__global__ __launch_bounds__(256) void k_expand1(const float* __restrict__ T0,
                                                 const float* __restrict__ T1,
                                                 const float* __restrict__ T2,
                                                 const float* __restrict__ T3,
                                                 const float* __restrict__ w1,
                                                 const float* __restrict__ b1,
                                                 float* __restrict__ H) {
    __shared__ float sT[4][64];
    __shared__ float sW[128];
    __shared__ float sB[32];
    int n = blockIdx.x, tid = threadIdx.x;
    {
        int k = tid >> 6, b = tid & 63;
        const float* Tk = (k == 0) ? T0 : (k == 1) ? T1 : (k == 2) ? T2 : T3;
        sT[k][b] = Tk[(size_t)n * 64 + b];
    }
    if (tid < 128) sW[tid] = w1[tid];
    if (tid < 32) sB[tid] = b1[tid];
    __syncthreads();
    int col0 = tid * 8;
    int b = tid >> 2;           // col0>>5
    int co0 = col0 & 31;
    float t0 = sT[0][b], t1 = sT[1][b], t2 = sT[2][b], t3 = sT[3][b];
    size_t o = (size_t)n * 2048 + col0;
#pragma unroll
    for (int j = 0; j < 8; ++j) {
        int co = co0 + j;
        float r = t0 * sW[co] + t1 * sW[32 + co] + t2 * sW[64 + co] + t3 * sW[96 + co] + sB[co];
        H[o + j] = r > 0.f ? r : 0.f;
    }
}

// ---------------------------------------------------------------------------
// Pure wide SpMM: Tout = (Pown ? 2*(L@Zg) - Pown : L@Zg)
// Width 2048; chunk = blockIdx&7 == XCD for L2 slice locality.
// ---------------------------------------------------------------------------
__global__ __launch_bounds__(256) void k_spmm_pure(const int* __restrict__ rowptr,
                                                   const int2* __restrict__ cv,
                                                   const float* __restrict__ Zg,
                                                   const float* __restrict__ Pown,
                                                   float* __restrict__ Tout) {
    int chunk = blockIdx.x & 7;
    int rowblk = blockIdx.x >> 3;
    int wave = threadIdx.x >> 6;
    int lane = threadIdx.x & 63;
    int n = rowblk * 4 + wave;
    int col0 = chunk * 256 + lane * 4;

    int start = rowptr[n], end = rowptr[n + 1];
    f4 acc0 = {0.f, 0.f, 0.f, 0.f}, acc1 = {0.f, 0.f, 0.f, 0.f};
    for (int e = start; e < end; e += 8) {
        const int4* q = reinterpret_cast<const int4*>(cv + e);
        int4 a = q[0], b = q[1], c = q[2], d = q[3];
        f4 z0 = *reinterpret_cast<const f4*>(Zg + (((size_t)a.x) << 11) + col0);
        f4 z1 = *reinterpret_cast<const f4*>(Zg + (((size_t)a.z) << 11) + col0);
        f4 z2 = *reinterpret_cast<const f4*>(Zg + (((size_t)b.x) << 11) + col0);
        f4 z3 = *reinterpret_cast<const f4*>(Zg + (((size_t)b.z) << 11) + col0);
        f4 z4 = *reinterpret_cast<const f4*>(Zg + (((size_t)c.x) << 11) + col0);
        f4 z5 = *reinterpret_cast<const f4*>(Zg + (((size_t)c.z) << 11) + col0);
        f4 z6 = *reinterpret_cast<const f4*>(Zg + (((size_t)d.x) << 11) + col0);
        f4 z7 = *reinterpret_cast<const f4*>(Zg + (((size_t)d.z) << 11) + col0);
        acc0 += __int_as_float(a.y) * z0;
        acc1 += __int_as_float(a.w) * z1;
        acc0 += __int_as_float(b.y) * z2;
        acc1 += __int_as_float(b.w) * z3;
        acc0 += __int_as_float(c.y) * z4;
        acc1 += __int_as_float(c.w) * z5;
        acc0 += __int_as_float(d.y) * z6;
        acc1 += __int_as_float(d.w) * z7;
    }
    size_t o = (((size_t)n) << 11) + col0;
    f4 t = acc0 + acc1;
    if (Pown) {
        f4 pp = *reinterpret_cast<const f4*>(Pown + o);
        t = 2.f * t - pp;
    }
    *reinterpret_cast<f4*>(Tout + o) = t;
}

// ---------------------------------------------------------------------------
// Chebyshev layer finalizer: computes T3 = 2*(L@T2g) - T1 in-register and
//   OUT = relu( H*W0 + T1*W1 + T2*W2 + T3*W3 + bias )
// W layout: [4][32][COUT] flat. T1 own-row doubles as the recurrence Pown.
// Two weight rounds (W3,W2 then W1,W0) keep LDS small for occupancy.
// ---------------------------------------------------------------------------
template <int COUT>
__global__ __launch_bounds__(256) void k_cheb_out(
    const int* __restrict__ rowptr, const int2* __restrict__ cv,
    const float* __restrict__ T2g,   // gather source (T2), also own-row read
    const float* __restrict__ T1,    // own-row: Pown + W1 operand
    const float* __restrict__ H,     // own-row: W0 operand
    const float* __restrict__ W,     // [4*32*COUT]
    const float* __restrict__ bias,  // [COUT]
    float* __restrict__ OUT)
{
    __shared__ float sW[2][32 * COUT];
    __shared__ float sP[4][2][264];

    int chunk = blockIdx.x & 7;
    int rowblk = blockIdx.x >> 3;
    int wave = threadIdx.x >> 6;
    int lane = threadIdx.x & 63;
    int n = rowblk * 4 + wave;
    int col0 = chunk * 256 + lane * 4;
    int tid = threadIdx.x;

    // round A weights: planes {W2, W3}
    for (int idx = tid; idx < 2 * 32 * COUT; idx += 256)
        sW[0][idx] = W[2 * 32 * COUT + idx];

    int start = rowptr[n], end = rowptr[n + 1];
    f4 acc0 = {0.f, 0.f, 0.f, 0.f}, acc1 = {0.f, 0.f, 0.f, 0.f};
    for (int e = start; e < end; e += 8) {
        const int4* q = reinterpret_cast<const int4*>(cv + e);
        int4 a = q[0], b = q[1], c = q[2], d = q[3];
        f4 z0 = *reinterpret_cast<const f4*>(T2g + (((size_t)a.x) << 11) + col0);
        f4 z1 = *reinterpret_cast<const f4*>(T2g + (((size_t)a.z) << 11) + col0);
        f4 z2 = *reinterpret_cast<const f4*>(T2g + (((size_t)b.x) << 11) + col0);
        f4 z3 = *reinterpret_cast<const f4*>(T2g + (((size_t)b.z) << 11) + col0);
        f4 z4 = *reinterpret_cast<const f4*>(T2g + (((size_t)c.x) << 11) + col0);
        f4 z5 = *reinterpret_cast<const f4*>(T2g + (((size_t)c.z) << 11) + col0);
        f4 z6 = *reinterpret_cast<const f4*>(T2g + (((size_t)d.x) << 11) + col0);
        f4 z7 = *reinterpret_cast<const f4*>(T2g + (((size_t)d.z) << 11) + col0);
        acc0 += __int_as_float(a.y) * z0;
        acc1 += __int_as_float(a.w) * z1;
        acc0 += __int_as_float(b.y) * z2;
        acc1 += __int_as_float(b.w) * z3;
        acc0 += __int_as_float(c.y) * z4;
        acc1 += __int_as_float(c.w) * z5;
        acc0 += __int_as_float(d.y) * z6;
        acc1 += __int_as_float(d.w) * z7;
    }
    size_t o = (((size_t)n) << 11) + col0;
    f4 pp  = *reinterpret_cast<const f4*>(T1 + o);    // T1 own (Pown + W1 operand)
    f4 t2o = *reinterpret_cast<const f4*>(T2g + o);   // T2 own
    f4 hh  = *reinterpret_cast<const f4*>(H + o);     // H own
    f4 t3 = 2.f * (acc0 + acc1) - pp;

    int g = lane >> 3, pq = lane & 7;
    float* p0 = &sP[wave][0][0];
    float* p1 = &sP[wave][1][0];
    int si = g * 33 + pq * 4;

    // ---- round A: T3 (W3 plane=sW[1]) and T2 (W2 plane=sW[0]) ----
    p0[si + 0] = t3.x; p0[si + 1] = t3.y; p0[si + 2] = t3.z; p0[si + 3] = t3.w;
    p1[si + 0] = t2o.x; p1[si + 1] = t2o.y; p1[si + 2] = t2o.z; p1[si + 3] = t2o.w;
    __syncthreads();

    float o0 = 0.f, o1 = 0.f, o2 = 0.f, o3 = 0.f;
    if constexpr (COUT == 32) {
        int co0 = pq * 4;
#pragma unroll
        for (int ci = 0; ci < 32; ++ci) {
            float a3 = p0[g * 33 + ci], a2 = p1[g * 33 + ci];
            o0 += a3 * sW[1][ci * 32 + co0 + 0] + a2 * sW[0][ci * 32 + co0 + 0];
            o1 += a3 * sW[1][ci * 32 + co0 + 1] + a2 * sW[0][ci * 32 + co0 + 1];
            o2 += a3 * sW[1][ci * 32 + co0 + 2] + a2 * sW[0][ci * 32 + co0 + 2];
            o3 += a3 * sW[1][ci * 32 + co0 + 3] + a2 * sW[0][ci * 32 + co0 + 3];
        }
    } else {
        if (lane < 32) {
            int gg = lane >> 2, co = lane & 3;
#pragma unroll
            for (int ci = 0; ci < 32; ++ci)
                o0 += p0[gg * 33 + ci] * sW[1][ci * 4 + co]
                    + p1[gg * 33 + ci] * sW[0][ci * 4 + co];
        }
    }
    __syncthreads();   // round A consumed

    // ---- round B: T1 (W1 plane=sW[1]) and H (W0 plane=sW[0]) ----
    for (int idx = tid; idx < 2 * 32 * COUT; idx += 256) sW[0][idx] = W[idx];
    p0[si + 0] = pp.x; p0[si + 1] = pp.y; p0[si + 2] = pp.z; p0[si + 3] = pp.w;
    p1[si + 0] = hh.x; p1[si + 1] = hh.y; p1[si + 2] = hh.z; p1[si + 3] = hh.w;
    __syncthreads();

    if constexpr (COUT == 32) {
        int co0 = pq * 4;
#pragma unroll
        for (int ci = 0; ci < 32; ++ci) {
            float a1 = p0[g * 33 + ci], a0 = p1[g * 33 + ci];
            o0 += a1 * sW[1][ci * 32 + co0 + 0] + a0 * sW[0][ci * 32 + co0 + 0];
            o1 += a1 * sW[1][ci * 32 + co0 + 1] + a0 * sW[0][ci * 32 + co0 + 1];
            o2 += a1 * sW[1][ci * 32 + co0 + 2] + a0 * sW[0][ci * 32 + co0 + 2];
            o3 += a1 * sW[1][ci * 32 + co0 + 3] + a0 * sW[0][ci * 32 + co0 + 3];
        }
        int co0b = pq * 4;
        f4 r;
        r.x = o0 + bias[co0b + 0];
        r.y = o1 + bias[co0b + 1];
        r.z = o2 + bias[co0b + 2];
        r.w = o3 + bias[co0b + 3];
        r.x = r.x > 0.f ? r.x : 0.f;
        r.y = r.y > 0.f ? r.y : 0.f;
        r.z = r.z > 0.f ? r.z : 0.f;
        r.w = r.w > 0.f ? r.w : 0.f;
        *reinterpret_cast<f4*>(OUT + o) = r;
    } else {
        if (lane < 32) {
            int gg = lane >> 2, co = lane & 3;
#pragma unroll
            for (int ci = 0; ci < 32; ++ci)
                o0 += p0[gg * 33 + ci] * sW[1][ci * 4 + co]
                    + p1[gg * 33 + ci] * sW[0][ci * 4 + co];
            float r = o0 + bias[co];
            r = r > 0.f ? r : 0.f;
            OUT[n * 256 + chunk * 32 + lane] = r;   // col = b*4+co, b = chunk*8+gg
        }
    }
}

// ---------------------------------------------------------------------------
// FC1: split-K over 128 blocks, atomic accumulate. h[b, n*4+c] = H5[n, b*4+c]
// ---------------------------------------------------------------------------
__global__ __launch_bounds__(256) void k_fc1(const float* __restrict__ H5,
                                             const float* __restrict__ fw1,
                                             float* __restrict__ fc1out) {
    __shared__ float hT[128 * 65];
    __shared__ float wS[32 * 128];
    int tid = threadIdx.x;
    int n0 = blockIdx.x * 32;
    for (int idx = tid; idx < 8192; idx += 256) {
        int n_l = idx >> 8;
        int rem = idx & 255;
        int b = rem >> 2, c = rem & 3;
        int kk = n_l * 4 + c;
        hT[kk * 65 + b] = H5[(size_t)(n0 + n_l) * 256 + rem];
    }
    float acc[8][4];
#pragma unroll
    for (int i = 0; i < 8; ++i)
#pragma unroll
        for (int j = 0; j < 4; ++j) acc[i][j] = 0.f;
    int bq = tid >> 5;
    int jq = tid & 31;
    for (int kb = 0; kb < 128; kb += 32) {
        __syncthreads();
        for (int idx = tid; idx < 4096; idx += 256) {
            int kl = idx >> 7, j = idx & 127;
            wS[idx] = fw1[(size_t)(n0 * 4 + kb + kl) * 128 + j];
        }
        __syncthreads();
        for (int kl = 0; kl < 32; ++kl) {
            int kk = kb + kl;
            float4 w = *reinterpret_cast<const float4*>(&wS[kl * 128 + jq * 4]);
#pragma unroll
            for (int bi = 0; bi < 8; ++bi) {
                float h = hT[kk * 65 + bq * 8 + bi];
                acc[bi][0] += h * w.x;
                acc[bi][1] += h * w.y;
                acc[bi][2] += h * w.z;
                acc[bi][3] += h * w.w;
            }
        }
    }
#pragma unroll
    for (int bi = 0; bi < 8; ++bi)
#pragma unroll
        for (int ji = 0; ji < 4; ++ji)
            atomicAdd(&fc1out[(bq * 8 + bi) * 128 + jq * 4 + ji], acc[bi][ji]);
}

__global__ __launch_bounds__(128) void k_fc23(const float* __restrict__ fc1out,
                                              const float* __restrict__ fb1,
                                              const float* __restrict__ fw2,
                                              const float* __restrict__ fb2,
                                              const float* __restrict__ fw3,
                                              const float* __restrict__ fb3,
                                              float* __restrict__ out) {
    int b = blockIdx.x;
    int j = threadIdx.x;
    __shared__ float r[128];
    __shared__ float s1[128];
    r[j] = fc1out[b * 128 + j] + fb1[j];
    __syncthreads();
    float acc = fb2[j];
    for (int i = 0; i < 128; ++i) acc += r[i] * fw2[i * 128 + j];
    s1[j] = acc;
    __syncthreads();
    if (j < 9) {
        float a2 = fb3[j];
        for (int i = 0; i < 128; ++i) a2 += s1[i] * fw3[i * 9 + j];
        out[b * 9 + j] = a2;
    }
}

// ---------------------------------------------------------------------------
extern "C" void kernel_launch(void* const* d_in, const int* in_sizes, int n_in,
                              void* d_out, int out_size, void* d_ws, size_t ws_size,
                              hipStream_t stream) {
    const float* x   = (const float*)d_in[0];
    const int*   src = (const int*)d_in[1];
    const int*   dst = (const int*)d_in[2];
    const float* ew  = (const float*)d_in[3];
    const float* w1  = (const float*)d_in[4];
    const float* b1  = (const float*)d_in[5];
    const float* w2  = (const float*)d_in[6];
    const float* b2  = (const float*)d_in[7];
    const float* w3  = (const float*)d_in[8];
    const float* b3  = (const float*)d_in[9];
    const float* w4  = (const float*)d_in[10];
    const float* b4  = (const float*)d_in[11];
    const float* w5  = (const float*)d_in[12];
    const float* b5  = (const float*)d_in[13];
    const float* fw1 = (const float*)d_in[14];
    const float* fb1 = (const float*)d_in[15];
    const float* fw2 = (const float*)d_in[16];
    const float* fb2 = (const float*)d_in[17];
    const float* fw3 = (const float*)d_in[18];
    const float* fb3 = (const float*)d_in[19];
    float* out = (float*)d_out;

    char* p = (char*)d_ws;
    const size_t XBYTES = (size_t)NN * 2048 * 4;  // 32 MB
    float* X0 = (float*)(p + 0 * XBYTES);
    float* X1 = (float*)(p + 1 * XBYTES);
    float* X2 = (float*)(p + 2 * XBYTES);
    float* X3 = (float*)(p + 3 * XBYTES);
    size_t off = 4 * XBYTES;
    float* deg    = (float*)(p + off); off += (size_t)NN * 4;
    int*   cnt    = (int*)(p + off);   off += (size_t)NN * 4;
    int*   cursor = (int*)(p + off);   off += (size_t)NN * 4;
    int*   rowptr = (int*)(p + off);   off += (size_t)(NN + 4) * 4;
    int2*  cv     = (int2*)(p + off);  off += (size_t)EPAD * 8;
    float* fc1o   = (float*)(p + off); off += (size_t)BB * 128 * 4;
    float* xn0    = (float*)(p + off); off += (size_t)NN * 64 * 4;
    float* tn1    = (float*)(p + off); off += (size_t)NN * 64 * 4;
    float* tn2    = (float*)(p + off); off += (size_t)NN * 64 * 4;
    float* tn3    = (float*)(p + off); off += (size_t)NN * 64 * 4;
    if (off > ws_size) return;

    hipMemsetAsync(deg, 0, NN * 4, stream);
    hipMemsetAsync(cnt, 0, NN * 4, stream);
    hipMemsetAsync(cv, 0, (size_t)EPAD * 8, stream);  // pad edges = {col 0, val 0}
    hipMemsetAsync(fc1o, 0, BB * 128 * 4, stream);

    k_deg_hist<<<EE / 256, 256, 0, stream>>>(src, dst, ew, deg, cnt);
    k_scan<<<1, 1024, 0, stream>>>(cnt, rowptr, cursor);
    k_fill<<<EE / 256, 256, 0, stream>>>(src, dst, ew, deg, cursor, cv);
    k_transpose_x<<<NN / 64, 256, 0, stream>>>(x, xn0);

    // ------------------- layer 1 entirely narrow, then one expand
    k_spmm_narrow<<<NN, 64, 0, stream>>>(rowptr, cv, xn0, nullptr, tn1, 1.f, 0);
    k_spmm_narrow<<<NN, 64, 0, stream>>>(rowptr, cv, tn1, xn0, tn2, 2.f, 1);
    k_spmm_narrow<<<NN, 64, 0, stream>>>(rowptr, cv, tn2, tn1, tn3, 2.f, 1);
    k_expand1<<<NN, 256, 0, stream>>>(xn0, tn1, tn2, tn3, w1, b1, X3);  // H1 -> X3

    const int GRID = (NN / 4) * 8;
    // ------------------- layers 2-4: S1, S2 pure; S3 fused finalizer
    auto run32 = [&](const float* H, float* T1, float* T2, float* OUT,
                     const float* W, const float* B) {
        k_spmm_pure<<<GRID, 256, 0, stream>>>(rowptr, cv, H, nullptr, T1);
        k_spmm_pure<<<GRID, 256, 0, stream>>>(rowptr, cv, T1, H, T2);
        k_cheb_out<32><<<GRID, 256, 0, stream>>>(rowptr, cv, T2, T1, H, W, B, OUT);
    };
    run32(X3, X0, X1, X2, w2, b2);
    run32(X2, X3, X0, X1, w3, b3);
    run32(X1, X2, X3, X0, w4, b4);

    // ------------------- layer 5 (COUT=4): H=X0 -> H5 in X3 [N][256]
    float* H5 = X3;
    k_spmm_pure<<<GRID, 256, 0, stream>>>(rowptr, cv, X0, nullptr, X1);
    k_spmm_pure<<<GRID, 256, 0, stream>>>(rowptr, cv, X1, X0, X2);
    k_cheb_out<4><<<GRID, 256, 0, stream>>>(rowptr, cv, X2, X1, X0, w5, b5, H5);

    // ------------------- FC head
    k_fc1<<<128, 256, 0, stream>>>(H5, fw1, fc1o);
    k_fc23<<<BB, 128, 0, stream>>>(fc1o, fb1, fw2, fb2, fw3, fb3, out);
}

// Round 6
// 962.410 us; speedup vs baseline: 1.4707x; 1.4707x over previous
//
#include <hip/hip_runtime.h>
#include <cstdint>

#define NN 4096
#define EE 131072
#define BB 64
#define EPAD (EE + 8 * NN)   // CSR rows padded to multiples of 8

typedef float f4 __attribute__((ext_vector_type(4)));

// ---------------------------------------------------------------------------
// Graph preprocessing
// ---------------------------------------------------------------------------
__global__ void k_deg_hist(const int* __restrict__ src, const int* __restrict__ dst,
                           const float* __restrict__ ew, float* __restrict__ deg,
                           int* __restrict__ cnt) {
    int e = blockIdx.x * blockDim.x + threadIdx.x;
    if (e >= EE) return;
    atomicAdd(&deg[src[e]], ew[e]);
    atomicAdd(&cnt[dst[e]], 1);
}

// scan of per-row counts PADDED to multiples of 8 -> uniform, tail-free SpMM loops
__global__ __launch_bounds__(1024) void k_scan(const int* __restrict__ cnt,
                                               int* __restrict__ rowptr,
                                               int* __restrict__ cursor) {
    __shared__ int s[1024];
    int tid = threadIdx.x;
    int p0 = (cnt[tid * 4 + 0] + 7) & ~7;
    int p1 = (cnt[tid * 4 + 1] + 7) & ~7;
    int p2 = (cnt[tid * 4 + 2] + 7) & ~7;
    int p3 = (cnt[tid * 4 + 3] + 7) & ~7;
    int sum = p0 + p1 + p2 + p3;
    s[tid] = sum;
    __syncthreads();
    for (int off = 1; off < 1024; off <<= 1) {
        int t = (tid >= off) ? s[tid - off] : 0;
        __syncthreads();
        s[tid] += t;
        __syncthreads();
    }
    int excl = s[tid] - sum;
    rowptr[tid * 4 + 0] = excl; cursor[tid * 4 + 0] = excl; excl += p0;
    rowptr[tid * 4 + 1] = excl; cursor[tid * 4 + 1] = excl; excl += p1;
    rowptr[tid * 4 + 2] = excl; cursor[tid * 4 + 2] = excl; excl += p2;
    rowptr[tid * 4 + 3] = excl; cursor[tid * 4 + 3] = excl; excl += p3;
    if (tid == 1023) rowptr[4096] = excl;
}

// cv[pos] = (col, val_bits); pad slots stay {0, 0.0f} from the memset
__global__ void k_fill(const int* __restrict__ src, const int* __restrict__ dst,
                       const float* __restrict__ ew, const float* __restrict__ deg,
                       int* __restrict__ cursor, int2* __restrict__ cv) {
    int e = blockIdx.x * blockDim.x + threadIdx.x;
    if (e >= EE) return;
    int s = src[e], d = dst[e];
    int pos = atomicAdd(&cursor[d], 1);
    float ds = deg[s], dd = deg[d];
    float is = ds > 0.f ? rsqrtf(fmaxf(ds, 1e-30f)) : 0.f;
    float id = dd > 0.f ? rsqrtf(fmaxf(dd, 1e-30f)) : 0.f;
    float v = -(is * ew[e] * id);
    cv[pos] = make_int2(s, __float_as_int(v));
}

// ---------------------------------------------------------------------------
// Transpose x [B,N] -> X0 [N,B]
// ---------------------------------------------------------------------------
__global__ __launch_bounds__(256) void k_transpose_x(const float* __restrict__ x,
                                                     float* __restrict__ X0) {
    __shared__ float s[64 * 65];
    int n0 = blockIdx.x * 64;
    for (int idx = threadIdx.x; idx < 4096; idx += 256) {
        int b = idx >> 6, nl = idx & 63;
        s[nl * 65 + b] = x[(size_t)b * NN + n0 + nl];
    }
    __syncthreads();
    for (int idx = threadIdx.x; idx < 4096; idx += 256) {
        int nl = idx >> 6, b = idx & 63;
        X0[(size_t)(n0 + nl) * 64 + b] = s[nl * 65 + b];
    }
}

// ---------------------------------------------------------------------------
// SpMM narrow (width 64, layer 1), tail-free x8 gather loop
// ---------------------------------------------------------------------------
__global__ __launch_bounds__(64) void k_spmm_narrow(const int* __restrict__ rowptr,
                                                    const int2* __restrict__ cv,
                                                    const float* __restrict__ Zin,
                                                    const float* __restrict__ Tprev,
                                                    float* __restrict__ Tout,
                                                    float alpha, int useprev) {
    int n = blockIdx.x;
    int lane = threadIdx.x;
    int start = rowptr[n], end = rowptr[n + 1];
    float acc = 0.f;
    for (int e = start; e < end; e += 8) {
        const int4* q = reinterpret_cast<const int4*>(cv + e);  // 16B aligned
        int4 a = q[0], b = q[1], c = q[2], d = q[3];
        float z0 = Zin[((size_t)a.x << 6) + lane];
        float z1 = Zin[((size_t)a.z << 6) + lane];
        float z2 = Zin[((size_t)b.x << 6) + lane];
        float z3 = Zin[((size_t)b.z << 6) + lane];
        float z4 = Zin[((size_t)c.x << 6) + lane];
        float z5 = Zin[((size_t)c.z << 6) + lane];
        float z6 = Zin[((size_t)d.x << 6) + lane];
        float z7 = Zin[((size_t)d.z << 6) + lane];
        acc += __int_as_float(a.y) * z0 + __int_as_float(a.w) * z1
             + __int_as_float(b.y) * z2 + __int_as_float(b.w) * z3
             + __int_as_float(c.y) * z4 + __int_as_float(c.w) * z5
             + __int_as_float(d.y) * z6 + __int_as_float(d.w) * z7;
    }
    size_t o = ((size_t)n << 6) + lane;
    float r = alpha * acc;
    if (useprev) r -= Tprev[o];
    Tout[o] = r;
}

// ---------------------------------------------------------------------------
// Layer-1 expand: H[n, b*32+co] = relu( sum_k Tk[n,b] * w1[k,co] + b1[co] )
// ---------------------------------------------------------------------------
__global__ __launch_bounds__(256) void k_expand1(const float* __restrict__ T0,
                                                 const float* __restrict__ T1,
                                                 const float* __restrict__ T2,
                                                 const float* __restrict__ T3,
                                                 const float* __restrict__ w1,
                                                 const float* __restrict__ b1,
                                                 float* __restrict__ H) {
    __shared__ float sT[4][64];
    __shared__ float sW[128];
    __shared__ float sB[32];
    int n = blockIdx.x, tid = threadIdx.x;
    {
        int k = tid >> 6, b = tid & 63;
        const float* Tk = (k == 0) ? T0 : (k == 1) ? T1 : (k == 2) ? T2 : T3;
        sT[k][b] = Tk[(size_t)n * 64 + b];
    }
    if (tid < 128) sW[tid] = w1[tid];
    if (tid < 32) sB[tid] = b1[tid];
    __syncthreads();
    int col0 = tid * 8;
    int b = tid >> 2;
    int co0 = col0 & 31;
    float t0 = sT[0][b], t1 = sT[1][b], t2 = sT[2][b], t3 = sT[3][b];
    size_t o = (size_t)n * 2048 + col0;
#pragma unroll
    for (int j = 0; j < 8; ++j) {
        int co = co0 + j;
        float r = t0 * sW[co] + t1 * sW[32 + co] + t2 * sW[64 + co] + t3 * sW[96 + co] + sB[co];
        H[o + j] = r > 0.f ? r : 0.f;
    }
}

// ---------------------------------------------------------------------------
// Pure wide SpMM: Tout = (Pown ? 2*(L@Zg) - Pown : L@Zg)
// ---------------------------------------------------------------------------
__global__ __launch_bounds__(256) void k_spmm_pure(const int* __restrict__ rowptr,
                                                   const int2* __restrict__ cv,
                                                   const float* __restrict__ Zg,
                                                   const float* __restrict__ Pown,
                                                   float* __restrict__ Tout) {
    int chunk = blockIdx.x & 7;
    int rowblk = blockIdx.x >> 3;
    int wave = threadIdx.x >> 6;
    int lane = threadIdx.x & 63;
    int n = rowblk * 4 + wave;
    int col0 = chunk * 256 + lane * 4;

    int start = rowptr[n], end = rowptr[n + 1];
    f4 acc0 = {0.f, 0.f, 0.f, 0.f}, acc1 = {0.f, 0.f, 0.f, 0.f};
    for (int e = start; e < end; e += 8) {
        const int4* q = reinterpret_cast<const int4*>(cv + e);
        int4 a = q[0], b = q[1], c = q[2], d = q[3];
        f4 z0 = *reinterpret_cast<const f4*>(Zg + (((size_t)a.x) << 11) + col0);
        f4 z1 = *reinterpret_cast<const f4*>(Zg + (((size_t)a.z) << 11) + col0);
        f4 z2 = *reinterpret_cast<const f4*>(Zg + (((size_t)b.x) << 11) + col0);
        f4 z3 = *reinterpret_cast<const f4*>(Zg + (((size_t)b.z) << 11) + col0);
        f4 z4 = *reinterpret_cast<const f4*>(Zg + (((size_t)c.x) << 11) + col0);
        f4 z5 = *reinterpret_cast<const f4*>(Zg + (((size_t)c.z) << 11) + col0);
        f4 z6 = *reinterpret_cast<const f4*>(Zg + (((size_t)d.x) << 11) + col0);
        f4 z7 = *reinterpret_cast<const f4*>(Zg + (((size_t)d.z) << 11) + col0);
        acc0 += __int_as_float(a.y) * z0;
        acc1 += __int_as_float(a.w) * z1;
        acc0 += __int_as_float(b.y) * z2;
        acc1 += __int_as_float(b.w) * z3;
        acc0 += __int_as_float(c.y) * z4;
        acc1 += __int_as_float(c.w) * z5;
        acc0 += __int_as_float(d.y) * z6;
        acc1 += __int_as_float(d.w) * z7;
    }
    size_t o = (((size_t)n) << 11) + col0;
    f4 t = acc0 + acc1;
    if (Pown) {
        f4 pp = *reinterpret_cast<const f4*>(Pown + o);
        t = 2.f * t - pp;
    }
    *reinterpret_cast<f4*>(Tout + o) = t;
}

// ---------------------------------------------------------------------------
// Chebyshev layer finalizer (single-round, occupancy-friendly):
//   T3 = 2*(L@T2g) - T1  (in-register)
//   OUT = relu( H*W0 + T1*W1 + T2*W2 + T3*W3 + bias )
// All 4 weight planes staged to LDS up front; all 4 operand planes staged to
// LDS; ONE barrier; broadcast-friendly dot. __launch_bounds__(256,4) caps
// VGPR at 128 (4 blocks/CU, matching 33KB LDS).
// ---------------------------------------------------------------------------
template <int COUT>
__global__ __launch_bounds__(256, 4) void k_cheb_out(
    const int* __restrict__ rowptr, const int2* __restrict__ cv,
    const float* __restrict__ T2g,   // gather source (T2), also own-row read
    const float* __restrict__ T1,    // own-row: Pown + W1 operand
    const float* __restrict__ H,     // own-row: W0 operand
    const float* __restrict__ W,     // [4*32*COUT] planes {W0,W1,W2,W3}
    const float* __restrict__ bias,  // [COUT]
    float* __restrict__ OUT)
{
    __shared__ float sW[4 * 32 * COUT];
    __shared__ float sP[4][4][264];  // [wave][plane H,T1,T2,T3][8*33]

    int chunk = blockIdx.x & 7;
    int rowblk = blockIdx.x >> 3;
    int wave = threadIdx.x >> 6;
    int lane = threadIdx.x & 63;
    int n = rowblk * 4 + wave;
    int col0 = chunk * 256 + lane * 4;
    int tid = threadIdx.x;

    // stage all weights global->LDS immediately (no long-lived registers)
    for (int idx = tid; idx < 4 * 32 * COUT; idx += 256) sW[idx] = W[idx];

    int start = rowptr[n], end = rowptr[n + 1];
    f4 acc0 = {0.f, 0.f, 0.f, 0.f}, acc1 = {0.f, 0.f, 0.f, 0.f};
    for (int e = start; e < end; e += 8) {
        const int4* q = reinterpret_cast<const int4*>(cv + e);
        int4 a = q[0], b = q[1], c = q[2], d = q[3];
        f4 z0 = *reinterpret_cast<const f4*>(T2g + (((size_t)a.x) << 11) + col0);
        f4 z1 = *reinterpret_cast<const f4*>(T2g + (((size_t)a.z) << 11) + col0);
        f4 z2 = *reinterpret_cast<const f4*>(T2g + (((size_t)b.x) << 11) + col0);
        f4 z3 = *reinterpret_cast<const f4*>(T2g + (((size_t)b.z) << 11) + col0);
        f4 z4 = *reinterpret_cast<const f4*>(T2g + (((size_t)c.x) << 11) + col0);
        f4 z5 = *reinterpret_cast<const f4*>(T2g + (((size_t)c.z) << 11) + col0);
        f4 z6 = *reinterpret_cast<const f4*>(T2g + (((size_t)d.x) << 11) + col0);
        f4 z7 = *reinterpret_cast<const f4*>(T2g + (((size_t)d.z) << 11) + col0);
        acc0 += __int_as_float(a.y) * z0;
        acc1 += __int_as_float(a.w) * z1;
        acc0 += __int_as_float(b.y) * z2;
        acc1 += __int_as_float(b.w) * z3;
        acc0 += __int_as_float(c.y) * z4;
        acc1 += __int_as_float(c.w) * z5;
        acc0 += __int_as_float(d.y) * z6;
        acc1 += __int_as_float(d.w) * z7;
    }
    size_t o = (((size_t)n) << 11) + col0;

    int g = lane >> 3, pq = lane & 7;
    int si = g * 33 + pq * 4;
    {   // T1 own-row -> t3 + plane 1; values die immediately after LDS store
        f4 pp = *reinterpret_cast<const f4*>(T1 + o);
        f4 t3 = 2.f * (acc0 + acc1) - pp;
        sP[wave][3][si + 0] = t3.x; sP[wave][3][si + 1] = t3.y;
        sP[wave][3][si + 2] = t3.z; sP[wave][3][si + 3] = t3.w;
        sP[wave][1][si + 0] = pp.x; sP[wave][1][si + 1] = pp.y;
        sP[wave][1][si + 2] = pp.z; sP[wave][1][si + 3] = pp.w;
    }
    {
        f4 t2o = *reinterpret_cast<const f4*>(T2g + o);
        sP[wave][2][si + 0] = t2o.x; sP[wave][2][si + 1] = t2o.y;
        sP[wave][2][si + 2] = t2o.z; sP[wave][2][si + 3] = t2o.w;
    }
    {
        f4 hh = *reinterpret_cast<const f4*>(H + o);
        sP[wave][0][si + 0] = hh.x; sP[wave][0][si + 1] = hh.y;
        sP[wave][0][si + 2] = hh.z; sP[wave][0][si + 3] = hh.w;
    }
    __syncthreads();  // covers sW and all sP planes

    const float* pH  = &sP[wave][0][0];
    const float* pT1 = &sP[wave][1][0];
    const float* pT2 = &sP[wave][2][0];
    const float* pT3 = &sP[wave][3][0];

    if constexpr (COUT == 32) {
        int co0 = pq * 4;
        f4 oacc = {0.f, 0.f, 0.f, 0.f};
#pragma unroll
        for (int ci = 0; ci < 32; ++ci) {
            float a0 = pH[g * 33 + ci], a1 = pT1[g * 33 + ci];
            float a2 = pT2[g * 33 + ci], a3 = pT3[g * 33 + ci];
            f4 w0 = *reinterpret_cast<const f4*>(&sW[0 * 1024 + ci * 32 + co0]);
            f4 w1 = *reinterpret_cast<const f4*>(&sW[1 * 1024 + ci * 32 + co0]);
            f4 w2 = *reinterpret_cast<const f4*>(&sW[2 * 1024 + ci * 32 + co0]);
            f4 w3 = *reinterpret_cast<const f4*>(&sW[3 * 1024 + ci * 32 + co0]);
            oacc += a0 * w0;
            oacc += a1 * w1;
            oacc += a2 * w2;
            oacc += a3 * w3;
        }
        f4 r;
        r.x = oacc.x + bias[co0 + 0];
        r.y = oacc.y + bias[co0 + 1];
        r.z = oacc.z + bias[co0 + 2];
        r.w = oacc.w + bias[co0 + 3];
        r.x = r.x > 0.f ? r.x : 0.f;
        r.y = r.y > 0.f ? r.y : 0.f;
        r.z = r.z > 0.f ? r.z : 0.f;
        r.w = r.w > 0.f ? r.w : 0.f;
        *reinterpret_cast<f4*>(OUT + o) = r;
    } else {  // COUT == 4, OUT width 256: col = b*4 + co
        if (lane < 32) {
            int gg = lane >> 2, co = lane & 3;
            float o0 = 0.f;
#pragma unroll
            for (int ci = 0; ci < 32; ++ci) {
                o0 += pH[gg * 33 + ci]  * sW[0 * 128 + ci * 4 + co]
                    + pT1[gg * 33 + ci] * sW[1 * 128 + ci * 4 + co]
                    + pT2[gg * 33 + ci] * sW[2 * 128 + ci * 4 + co]
                    + pT3[gg * 33 + ci] * sW[3 * 128 + ci * 4 + co];
            }
            float r = o0 + bias[co];
            r = r > 0.f ? r : 0.f;
            OUT[n * 256 + chunk * 32 + lane] = r;
        }
    }
}

// ---------------------------------------------------------------------------
// FC1: split-K over 128 blocks, atomic accumulate. h[b, n*4+c] = H5[n, b*4+c]
// ---------------------------------------------------------------------------
__global__ __launch_bounds__(256) void k_fc1(const float* __restrict__ H5,
                                             const float* __restrict__ fw1,
                                             float* __restrict__ fc1out) {
    __shared__ float hT[128 * 65];
    __shared__ float wS[32 * 128];
    int tid = threadIdx.x;
    int n0 = blockIdx.x * 32;
    for (int idx = tid; idx < 8192; idx += 256) {
        int n_l = idx >> 8;
        int rem = idx & 255;
        int b = rem >> 2, c = rem & 3;
        int kk = n_l * 4 + c;
        hT[kk * 65 + b] = H5[(size_t)(n0 + n_l) * 256 + rem];
    }
    float acc[8][4];
#pragma unroll
    for (int i = 0; i < 8; ++i)
#pragma unroll
        for (int j = 0; j < 4; ++j) acc[i][j] = 0.f;
    int bq = tid >> 5;
    int jq = tid & 31;
    for (int kb = 0; kb < 128; kb += 32) {
        __syncthreads();
        for (int idx = tid; idx < 4096; idx += 256) {
            int kl = idx >> 7, j = idx & 127;
            wS[idx] = fw1[(size_t)(n0 * 4 + kb + kl) * 128 + j];
        }
        __syncthreads();
        for (int kl = 0; kl < 32; ++kl) {
            int kk = kb + kl;
            float4 w = *reinterpret_cast<const float4*>(&wS[kl * 128 + jq * 4]);
#pragma unroll
            for (int bi = 0; bi < 8; ++bi) {
                float h = hT[kk * 65 + bq * 8 + bi];
                acc[bi][0] += h * w.x;
                acc[bi][1] += h * w.y;
                acc[bi][2] += h * w.z;
                acc[bi][3] += h * w.w;
            }
        }
    }
#pragma unroll
    for (int bi = 0; bi < 8; ++bi)
#pragma unroll
        for (int ji = 0; ji < 4; ++ji)
            atomicAdd(&fc1out[(bq * 8 + bi) * 128 + jq * 4 + ji], acc[bi][ji]);
}

__global__ __launch_bounds__(128) void k_fc23(const float* __restrict__ fc1out,
                                              const float* __restrict__ fb1,
                                              const float* __restrict__ fw2,
                                              const float* __restrict__ fb2,
                                              const float* __restrict__ fw3,
                                              const float* __restrict__ fb3,
                                              float* __restrict__ out) {
    int b = blockIdx.x;
    int j = threadIdx.x;
    __shared__ float r[128];
    __shared__ float s1[128];
    r[j] = fc1out[b * 128 + j] + fb1[j];
    __syncthreads();
    float acc = fb2[j];
    for (int i = 0; i < 128; ++i) acc += r[i] * fw2[i * 128 + j];
    s1[j] = acc;
    __syncthreads();
    if (j < 9) {
        float a2 = fb3[j];
        for (int i = 0; i < 128; ++i) a2 += s1[i] * fw3[i * 9 + j];
        out[b * 9 + j] = a2;
    }
}

// ---------------------------------------------------------------------------
extern "C" void kernel_launch(void* const* d_in, const int* in_sizes, int n_in,
                              void* d_out, int out_size, void* d_ws, size_t ws_size,
                              hipStream_t stream) {
    const float* x   = (const float*)d_in[0];
    const int*   src = (const int*)d_in[1];
    const int*   dst = (const int*)d_in[2];
    const float* ew  = (const float*)d_in[3];
    const float* w1  = (const float*)d_in[4];
    const float* b1  = (const float*)d_in[5];
    const float* w2  = (const float*)d_in[6];
    const float* b2  = (const float*)d_in[7];
    const float* w3  = (const float*)d_in[8];
    const float* b3  = (const float*)d_in[9];
    const float* w4  = (const float*)d_in[10];
    const float* b4  = (const float*)d_in[11];
    const float* w5  = (const float*)d_in[12];
    const float* b5  = (const float*)d_in[13];
    const float* fw1 = (const float*)d_in[14];
    const float* fb1 = (const float*)d_in[15];
    const float* fw2 = (const float*)d_in[16];
    const float* fb2 = (const float*)d_in[17];
    const float* fw3 = (const float*)d_in[18];
    const float* fb3 = (const float*)d_in[19];
    float* out = (float*)d_out;

    char* p = (char*)d_ws;
    const size_t XBYTES = (size_t)NN * 2048 * 4;  // 32 MB
    float* X0 = (float*)(p + 0 * XBYTES);
    float* X1 = (float*)(p + 1 * XBYTES);
    float* X2 = (float*)(p + 2 * XBYTES);
    float* X3 = (float*)(p + 3 * XBYTES);
    size_t off = 4 * XBYTES;
    float* deg    = (float*)(p + off); off += (size_t)NN * 4;
    int*   cnt    = (int*)(p + off);   off += (size_t)NN * 4;
    int*   cursor = (int*)(p + off);   off += (size_t)NN * 4;
    int*   rowptr = (int*)(p + off);   off += (size_t)(NN + 4) * 4;
    int2*  cv     = (int2*)(p + off);  off += (size_t)EPAD * 8;
    float* fc1o   = (float*)(p + off); off += (size_t)BB * 128 * 4;
    float* xn0    = (float*)(p + off); off += (size_t)NN * 64 * 4;
    float* tn1    = (float*)(p + off); off += (size_t)NN * 64 * 4;
    float* tn2    = (float*)(p + off); off += (size_t)NN * 64 * 4;
    float* tn3    = (float*)(p + off); off += (size_t)NN * 64 * 4;
    if (off > ws_size) return;

    hipMemsetAsync(deg, 0, NN * 4, stream);
    hipMemsetAsync(cnt, 0, NN * 4, stream);
    hipMemsetAsync(cv, 0, (size_t)EPAD * 8, stream);  // pad edges = {col 0, val 0}
    hipMemsetAsync(fc1o, 0, BB * 128 * 4, stream);

    k_deg_hist<<<EE / 256, 256, 0, stream>>>(src, dst, ew, deg, cnt);
    k_scan<<<1, 1024, 0, stream>>>(cnt, rowptr, cursor);
    k_fill<<<EE / 256, 256, 0, stream>>>(src, dst, ew, deg, cursor, cv);
    k_transpose_x<<<NN / 64, 256, 0, stream>>>(x, xn0);

    // ------------------- layer 1 entirely narrow, then one expand
    k_spmm_narrow<<<NN, 64, 0, stream>>>(rowptr, cv, xn0, nullptr, tn1, 1.f, 0);
    k_spmm_narrow<<<NN, 64, 0, stream>>>(rowptr, cv, tn1, xn0, tn2, 2.f, 1);
    k_spmm_narrow<<<NN, 64, 0, stream>>>(rowptr, cv, tn2, tn1, tn3, 2.f, 1);
    k_expand1<<<NN, 256, 0, stream>>>(xn0, tn1, tn2, tn3, w1, b1, X3);  // H1 -> X3

    const int GRID = (NN / 4) * 8;
    // ------------------- layers 2-4: S1, S2 pure; S3 fused finalizer
    auto run32 = [&](const float* H, float* T1, float* T2, float* OUT,
                     const float* W, const float* B) {
        k_spmm_pure<<<GRID, 256, 0, stream>>>(rowptr, cv, H, nullptr, T1);
        k_spmm_pure<<<GRID, 256, 0, stream>>>(rowptr, cv, T1, H, T2);
        k_cheb_out<32><<<GRID, 256, 0, stream>>>(rowptr, cv, T2, T1, H, W, B, OUT);
    };
    run32(X3, X0, X1, X2, w2, b2);
    run32(X2, X3, X0, X1, w3, b3);
    run32(X1, X2, X3, X0, w4, b4);

    // ------------------- layer 5 (COUT=4): H=X0 -> H5 in X3 [N][256]
    float* H5 = X3;
    k_spmm_pure<<<GRID, 256, 0, stream>>>(rowptr, cv, X0, nullptr, X1);
    k_spmm_pure<<<GRID, 256, 0, stream>>>(rowptr, cv, X1, X0, X2);
    k_cheb_out<4><<<GRID, 256, 0, stream>>>(rowptr, cv, X2, X1, X0, w5, b5, H5);

    // ------------------- FC head
    k_fc1<<<128, 256, 0, stream>>>(H5, fw1, fc1o);
    k_fc23<<<BB, 128, 0, stream>>>(fc1o, fb1, fw2, fb2, fw3, fb3, out);
}

// Round 7
// 864.708 us; speedup vs baseline: 1.6369x; 1.1130x over previous
//
#include <hip/hip_runtime.h>
#include <cstdint>

#define NN 4096
#define EE 131072
#define BB 64
#define EPAD (EE + 8 * NN)   // CSR rows padded to multiples of 8

typedef float f4 __attribute__((ext_vector_type(4)));
typedef unsigned short ushort_t;
typedef unsigned int uint_t;

// bf16 helpers: unpack 4 bf16 (uint2) -> f4 ; pack with RNE
__device__ __forceinline__ f4 up4(uint2 u) {
    f4 r;
    r.x = __uint_as_float(u.x << 16);
    r.y = __uint_as_float(u.x & 0xffff0000u);
    r.z = __uint_as_float(u.y << 16);
    r.w = __uint_as_float(u.y & 0xffff0000u);
    return r;
}
__device__ __forceinline__ uint_t bfpk(float a, float b) {
    uint_t xa = __float_as_uint(a); xa = (xa + 0x7fffu + ((xa >> 16) & 1u)) >> 16;
    uint_t xb = __float_as_uint(b); xb = (xb + 0x7fffu + ((xb >> 16) & 1u));
    return (xa & 0xffffu) | (xb & 0xffff0000u);
}

// ---------------------------------------------------------------------------
// Graph preprocessing
// ---------------------------------------------------------------------------
__global__ void k_deg_hist(const int* __restrict__ src, const int* __restrict__ dst,
                           const float* __restrict__ ew, float* __restrict__ deg,
                           int* __restrict__ cnt) {
    int e = blockIdx.x * blockDim.x + threadIdx.x;
    if (e >= EE) return;
    atomicAdd(&deg[src[e]], ew[e]);
    atomicAdd(&cnt[dst[e]], 1);
}

__global__ __launch_bounds__(1024) void k_scan(const int* __restrict__ cnt,
                                               int* __restrict__ rowptr,
                                               int* __restrict__ cursor) {
    __shared__ int s[1024];
    int tid = threadIdx.x;
    int p0 = (cnt[tid * 4 + 0] + 7) & ~7;
    int p1 = (cnt[tid * 4 + 1] + 7) & ~7;
    int p2 = (cnt[tid * 4 + 2] + 7) & ~7;
    int p3 = (cnt[tid * 4 + 3] + 7) & ~7;
    int sum = p0 + p1 + p2 + p3;
    s[tid] = sum;
    __syncthreads();
    for (int off = 1; off < 1024; off <<= 1) {
        int t = (tid >= off) ? s[tid - off] : 0;
        __syncthreads();
        s[tid] += t;
        __syncthreads();
    }
    int excl = s[tid] - sum;
    rowptr[tid * 4 + 0] = excl; cursor[tid * 4 + 0] = excl; excl += p0;
    rowptr[tid * 4 + 1] = excl; cursor[tid * 4 + 1] = excl; excl += p1;
    rowptr[tid * 4 + 2] = excl; cursor[tid * 4 + 2] = excl; excl += p2;
    rowptr[tid * 4 + 3] = excl; cursor[tid * 4 + 3] = excl; excl += p3;
    if (tid == 1023) rowptr[4096] = excl;
}

__global__ void k_fill(const int* __restrict__ src, const int* __restrict__ dst,
                       const float* __restrict__ ew, const float* __restrict__ deg,
                       int* __restrict__ cursor, int2* __restrict__ cv) {
    int e = blockIdx.x * blockDim.x + threadIdx.x;
    if (e >= EE) return;
    int s = src[e], d = dst[e];
    int pos = atomicAdd(&cursor[d], 1);
    float ds = deg[s], dd = deg[d];
    float is = ds > 0.f ? rsqrtf(fmaxf(ds, 1e-30f)) : 0.f;
    float id = dd > 0.f ? rsqrtf(fmaxf(dd, 1e-30f)) : 0.f;
    float v = -(is * ew[e] * id);
    cv[pos] = make_int2(s, __float_as_int(v));
}

// ---------------------------------------------------------------------------
// Transpose x [B,N] -> X0 [N,B]  (fp32, layer-1 narrow path)
// ---------------------------------------------------------------------------
__global__ __launch_bounds__(256) void k_transpose_x(const float* __restrict__ x,
                                                     float* __restrict__ X0) {
    __shared__ float s[64 * 65];
    int n0 = blockIdx.x * 64;
    for (int idx = threadIdx.x; idx < 4096; idx += 256) {
        int b = idx >> 6, nl = idx & 63;
        s[nl * 65 + b] = x[(size_t)b * NN + n0 + nl];
    }
    __syncthreads();
    for (int idx = threadIdx.x; idx < 4096; idx += 256) {
        int nl = idx >> 6, b = idx & 63;
        X0[(size_t)(n0 + nl) * 64 + b] = s[nl * 65 + b];
    }
}

// ---------------------------------------------------------------------------
// SpMM narrow (width 64, fp32, layer 1), tail-free x8 gather loop
// ---------------------------------------------------------------------------
__global__ __launch_bounds__(64) void k_spmm_narrow(const int* __restrict__ rowptr,
                                                    const int2* __restrict__ cv,
                                                    const float* __restrict__ Zin,
                                                    const float* __restrict__ Tprev,
                                                    float* __restrict__ Tout,
                                                    float alpha, int useprev) {
    int n = blockIdx.x;
    int lane = threadIdx.x;
    int start = rowptr[n], end = rowptr[n + 1];
    float acc = 0.f;
    for (int e = start; e < end; e += 8) {
        const int4* q = reinterpret_cast<const int4*>(cv + e);
        int4 a = q[0], b = q[1], c = q[2], d = q[3];
        float z0 = Zin[((size_t)a.x << 6) + lane];
        float z1 = Zin[((size_t)a.z << 6) + lane];
        float z2 = Zin[((size_t)b.x << 6) + lane];
        float z3 = Zin[((size_t)b.z << 6) + lane];
        float z4 = Zin[((size_t)c.x << 6) + lane];
        float z5 = Zin[((size_t)c.z << 6) + lane];
        float z6 = Zin[((size_t)d.x << 6) + lane];
        float z7 = Zin[((size_t)d.z << 6) + lane];
        acc += __int_as_float(a.y) * z0 + __int_as_float(a.w) * z1
             + __int_as_float(b.y) * z2 + __int_as_float(b.w) * z3
             + __int_as_float(c.y) * z4 + __int_as_float(c.w) * z5
             + __int_as_float(d.y) * z6 + __int_as_float(d.w) * z7;
    }
    size_t o = ((size_t)n << 6) + lane;
    float r = alpha * acc;
    if (useprev) r -= Tprev[o];
    Tout[o] = r;
}

// ---------------------------------------------------------------------------
// Layer-1 expand -> bf16 H: H[n, b*32+co] = relu( sum_k Tk[n,b]*w1[k,co]+b1 )
// ---------------------------------------------------------------------------
__global__ __launch_bounds__(256) void k_expand1(const float* __restrict__ T0,
                                                 const float* __restrict__ T1,
                                                 const float* __restrict__ T2,
                                                 const float* __restrict__ T3,
                                                 const float* __restrict__ w1,
                                                 const float* __restrict__ b1,
                                                 ushort_t* __restrict__ H) {
    __shared__ float sT[4][64];
    __shared__ float sW[128];
    __shared__ float sB[32];
    int n = blockIdx.x, tid = threadIdx.x;
    {
        int k = tid >> 6, b = tid & 63;
        const float* Tk = (k == 0) ? T0 : (k == 1) ? T1 : (k == 2) ? T2 : T3;
        sT[k][b] = Tk[(size_t)n * 64 + b];
    }
    if (tid < 128) sW[tid] = w1[tid];
    if (tid < 32) sB[tid] = b1[tid];
    __syncthreads();
    int col0 = tid * 8;
    int b = tid >> 2;
    int co0 = col0 & 31;
    float t0 = sT[0][b], t1 = sT[1][b], t2 = sT[2][b], t3 = sT[3][b];
    float r[8];
#pragma unroll
    for (int j = 0; j < 8; ++j) {
        int co = co0 + j;
        float v = t0 * sW[co] + t1 * sW[32 + co] + t2 * sW[64 + co] + t3 * sW[96 + co] + sB[co];
        r[j] = v > 0.f ? v : 0.f;
    }
    uint4 st;
    st.x = bfpk(r[0], r[1]); st.y = bfpk(r[2], r[3]);
    st.z = bfpk(r[4], r[5]); st.w = bfpk(r[6], r[7]);
    *reinterpret_cast<uint4*>(H + (size_t)n * 2048 + col0) = st;
}

// ---------------------------------------------------------------------------
// Pure wide SpMM on bf16 storage (fp32 accumulate):
//   Tout = (Pown ? 2*(L@Zg) - Pown : L@Zg)
// Width 2048 cols; chunk = blockIdx&7 == XCD; slice = 2MB bf16 -> L2-resident.
// ---------------------------------------------------------------------------
__global__ __launch_bounds__(256) void k_spmm_pure(const int* __restrict__ rowptr,
                                                   const int2* __restrict__ cv,
                                                   const ushort_t* __restrict__ Zg,
                                                   const ushort_t* __restrict__ Pown,
                                                   ushort_t* __restrict__ Tout) {
    int chunk = blockIdx.x & 7;
    int rowblk = blockIdx.x >> 3;
    int wave = threadIdx.x >> 6;
    int lane = threadIdx.x & 63;
    int n = rowblk * 4 + wave;
    int col0 = chunk * 256 + lane * 4;

    int start = rowptr[n], end = rowptr[n + 1];
    f4 acc0 = {0.f, 0.f, 0.f, 0.f}, acc1 = {0.f, 0.f, 0.f, 0.f};
    for (int e = start; e < end; e += 8) {
        const int4* q = reinterpret_cast<const int4*>(cv + e);
        int4 a = q[0], b = q[1], c = q[2], d = q[3];
        uint2 u0 = *reinterpret_cast<const uint2*>(Zg + (((size_t)a.x) << 11) + col0);
        uint2 u1 = *reinterpret_cast<const uint2*>(Zg + (((size_t)a.z) << 11) + col0);
        uint2 u2 = *reinterpret_cast<const uint2*>(Zg + (((size_t)b.x) << 11) + col0);
        uint2 u3 = *reinterpret_cast<const uint2*>(Zg + (((size_t)b.z) << 11) + col0);
        uint2 u4 = *reinterpret_cast<const uint2*>(Zg + (((size_t)c.x) << 11) + col0);
        uint2 u5 = *reinterpret_cast<const uint2*>(Zg + (((size_t)c.z) << 11) + col0);
        uint2 u6 = *reinterpret_cast<const uint2*>(Zg + (((size_t)d.x) << 11) + col0);
        uint2 u7 = *reinterpret_cast<const uint2*>(Zg + (((size_t)d.z) << 11) + col0);
        acc0 += __int_as_float(a.y) * up4(u0);
        acc1 += __int_as_float(a.w) * up4(u1);
        acc0 += __int_as_float(b.y) * up4(u2);
        acc1 += __int_as_float(b.w) * up4(u3);
        acc0 += __int_as_float(c.y) * up4(u4);
        acc1 += __int_as_float(c.w) * up4(u5);
        acc0 += __int_as_float(d.y) * up4(u6);
        acc1 += __int_as_float(d.w) * up4(u7);
    }
    size_t o = (((size_t)n) << 11) + col0;
    f4 t = acc0 + acc1;
    if (Pown) {
        f4 pp = up4(*reinterpret_cast<const uint2*>(Pown + o));
        t = 2.f * t - pp;
    }
    uint2 st;
    st.x = bfpk(t.x, t.y);
    st.y = bfpk(t.z, t.w);
    *reinterpret_cast<uint2*>(Tout + o) = st;
}

// ---------------------------------------------------------------------------
// Chebyshev finalizer on bf16 storage:
//   T3 = 2*(L@T2g) - T1  (fp32 in-register)
//   OUT = relu( H*W0 + T1*W1 + T2*W2 + T3*W3 + bias )
// OUTBF: write bf16 [N][2048] (layers 2-4) else fp32 [N][256] (layer 5).
// ---------------------------------------------------------------------------
template <int COUT, bool OUTBF>
__global__ __launch_bounds__(256, 4) void k_cheb_out(
    const int* __restrict__ rowptr, const int2* __restrict__ cv,
    const ushort_t* __restrict__ T2g,  // gather source (T2), also own-row read
    const ushort_t* __restrict__ T1,   // own-row: Pown + W1 operand
    const ushort_t* __restrict__ H,    // own-row: W0 operand
    const float* __restrict__ W,       // [4*32*COUT] planes {W0,W1,W2,W3}
    const float* __restrict__ bias,    // [COUT]
    void* __restrict__ OUTv)
{
    __shared__ float sW[4 * 32 * COUT];
    __shared__ float sP[4][4][264];  // [wave][plane H,T1,T2,T3][8*33]

    int chunk = blockIdx.x & 7;
    int rowblk = blockIdx.x >> 3;
    int wave = threadIdx.x >> 6;
    int lane = threadIdx.x & 63;
    int n = rowblk * 4 + wave;
    int col0 = chunk * 256 + lane * 4;
    int tid = threadIdx.x;

    for (int idx = tid; idx < 4 * 32 * COUT; idx += 256) sW[idx] = W[idx];

    int start = rowptr[n], end = rowptr[n + 1];
    f4 acc0 = {0.f, 0.f, 0.f, 0.f}, acc1 = {0.f, 0.f, 0.f, 0.f};
    for (int e = start; e < end; e += 8) {
        const int4* q = reinterpret_cast<const int4*>(cv + e);
        int4 a = q[0], b = q[1], c = q[2], d = q[3];
        uint2 u0 = *reinterpret_cast<const uint2*>(T2g + (((size_t)a.x) << 11) + col0);
        uint2 u1 = *reinterpret_cast<const uint2*>(T2g + (((size_t)a.z) << 11) + col0);
        uint2 u2 = *reinterpret_cast<const uint2*>(T2g + (((size_t)b.x) << 11) + col0);
        uint2 u3 = *reinterpret_cast<const uint2*>(T2g + (((size_t)b.z) << 11) + col0);
        uint2 u4 = *reinterpret_cast<const uint2*>(T2g + (((size_t)c.x) << 11) + col0);
        uint2 u5 = *reinterpret_cast<const uint2*>(T2g + (((size_t)c.z) << 11) + col0);
        uint2 u6 = *reinterpret_cast<const uint2*>(T2g + (((size_t)d.x) << 11) + col0);
        uint2 u7 = *reinterpret_cast<const uint2*>(T2g + (((size_t)d.z) << 11) + col0);
        acc0 += __int_as_float(a.y) * up4(u0);
        acc1 += __int_as_float(a.w) * up4(u1);
        acc0 += __int_as_float(b.y) * up4(u2);
        acc1 += __int_as_float(b.w) * up4(u3);
        acc0 += __int_as_float(c.y) * up4(u4);
        acc1 += __int_as_float(c.w) * up4(u5);
        acc0 += __int_as_float(d.y) * up4(u6);
        acc1 += __int_as_float(d.w) * up4(u7);
    }
    size_t o = (((size_t)n) << 11) + col0;

    int g = lane >> 3, pq = lane & 7;
    int si = g * 33 + pq * 4;
    {
        f4 pp = up4(*reinterpret_cast<const uint2*>(T1 + o));
        f4 t3 = 2.f * (acc0 + acc1) - pp;
        sP[wave][3][si + 0] = t3.x; sP[wave][3][si + 1] = t3.y;
        sP[wave][3][si + 2] = t3.z; sP[wave][3][si + 3] = t3.w;
        sP[wave][1][si + 0] = pp.x; sP[wave][1][si + 1] = pp.y;
        sP[wave][1][si + 2] = pp.z; sP[wave][1][si + 3] = pp.w;
    }
    {
        f4 t2o = up4(*reinterpret_cast<const uint2*>(T2g + o));
        sP[wave][2][si + 0] = t2o.x; sP[wave][2][si + 1] = t2o.y;
        sP[wave][2][si + 2] = t2o.z; sP[wave][2][si + 3] = t2o.w;
    }
    {
        f4 hh = up4(*reinterpret_cast<const uint2*>(H + o));
        sP[wave][0][si + 0] = hh.x; sP[wave][0][si + 1] = hh.y;
        sP[wave][0][si + 2] = hh.z; sP[wave][0][si + 3] = hh.w;
    }
    __syncthreads();

    const float* pH  = &sP[wave][0][0];
    const float* pT1 = &sP[wave][1][0];
    const float* pT2 = &sP[wave][2][0];
    const float* pT3 = &sP[wave][3][0];

    if constexpr (COUT == 32) {
        int co0 = pq * 4;
        f4 oacc = {0.f, 0.f, 0.f, 0.f};
#pragma unroll
        for (int ci = 0; ci < 32; ++ci) {
            float a0 = pH[g * 33 + ci], a1 = pT1[g * 33 + ci];
            float a2 = pT2[g * 33 + ci], a3 = pT3[g * 33 + ci];
            f4 w0 = *reinterpret_cast<const f4*>(&sW[0 * 1024 + ci * 32 + co0]);
            f4 w1 = *reinterpret_cast<const f4*>(&sW[1 * 1024 + ci * 32 + co0]);
            f4 w2 = *reinterpret_cast<const f4*>(&sW[2 * 1024 + ci * 32 + co0]);
            f4 w3 = *reinterpret_cast<const f4*>(&sW[3 * 1024 + ci * 32 + co0]);
            oacc += a0 * w0;
            oacc += a1 * w1;
            oacc += a2 * w2;
            oacc += a3 * w3;
        }
        f4 r;
        r.x = oacc.x + bias[co0 + 0];
        r.y = oacc.y + bias[co0 + 1];
        r.z = oacc.z + bias[co0 + 2];
        r.w = oacc.w + bias[co0 + 3];
        r.x = r.x > 0.f ? r.x : 0.f;
        r.y = r.y > 0.f ? r.y : 0.f;
        r.z = r.z > 0.f ? r.z : 0.f;
        r.w = r.w > 0.f ? r.w : 0.f;
        if constexpr (OUTBF) {
            uint2 st;
            st.x = bfpk(r.x, r.y);
            st.y = bfpk(r.z, r.w);
            *reinterpret_cast<uint2*>((ushort_t*)OUTv + o) = st;
        } else {
            *reinterpret_cast<f4*>((float*)OUTv + o) = r;
        }
    } else {  // COUT == 4, OUT width 256 fp32: col = b*4 + co
        if (lane < 32) {
            int gg = lane >> 2, co = lane & 3;
            float o0 = 0.f;
#pragma unroll
            for (int ci = 0; ci < 32; ++ci) {
                o0 += pH[gg * 33 + ci]  * sW[0 * 128 + ci * 4 + co]
                    + pT1[gg * 33 + ci] * sW[1 * 128 + ci * 4 + co]
                    + pT2[gg * 33 + ci] * sW[2 * 128 + ci * 4 + co]
                    + pT3[gg * 33 + ci] * sW[3 * 128 + ci * 4 + co];
            }
            float r = o0 + bias[co];
            r = r > 0.f ? r : 0.f;
            ((float*)OUTv)[n * 256 + chunk * 32 + lane] = r;
        }
    }
}

// ---------------------------------------------------------------------------
// FC1: split-K over 128 blocks, atomic accumulate. h[b, n*4+c] = H5[n, b*4+c]
// ---------------------------------------------------------------------------
__global__ __launch_bounds__(256) void k_fc1(const float* __restrict__ H5,
                                             const float* __restrict__ fw1,
                                             float* __restrict__ fc1out) {
    __shared__ float hT[128 * 65];
    __shared__ float wS[32 * 128];
    int tid = threadIdx.x;
    int n0 = blockIdx.x * 32;
    for (int idx = tid; idx < 8192; idx += 256) {
        int n_l = idx >> 8;
        int rem = idx & 255;
        int b = rem >> 2, c = rem & 3;
        int kk = n_l * 4 + c;
        hT[kk * 65 + b] = H5[(size_t)(n0 + n_l) * 256 + rem];
    }
    float acc[8][4];
#pragma unroll
    for (int i = 0; i < 8; ++i)
#pragma unroll
        for (int j = 0; j < 4; ++j) acc[i][j] = 0.f;
    int bq = tid >> 5;
    int jq = tid & 31;
    for (int kb = 0; kb < 128; kb += 32) {
        __syncthreads();
        for (int idx = tid; idx < 4096; idx += 256) {
            int kl = idx >> 7, j = idx & 127;
            wS[idx] = fw1[(size_t)(n0 * 4 + kb + kl) * 128 + j];
        }
        __syncthreads();
        for (int kl = 0; kl < 32; ++kl) {
            int kk = kb + kl;
            float4 w = *reinterpret_cast<const float4*>(&wS[kl * 128 + jq * 4]);
#pragma unroll
            for (int bi = 0; bi < 8; ++bi) {
                float h = hT[kk * 65 + bq * 8 + bi];
                acc[bi][0] += h * w.x;
                acc[bi][1] += h * w.y;
                acc[bi][2] += h * w.z;
                acc[bi][3] += h * w.w;
            }
        }
    }
#pragma unroll
    for (int bi = 0; bi < 8; ++bi)
#pragma unroll
        for (int ji = 0; ji < 4; ++ji)
            atomicAdd(&fc1out[(bq * 8 + bi) * 128 + jq * 4 + ji], acc[bi][ji]);
}

__global__ __launch_bounds__(128) void k_fc23(const float* __restrict__ fc1out,
                                              const float* __restrict__ fb1,
                                              const float* __restrict__ fw2,
                                              const float* __restrict__ fb2,
                                              const float* __restrict__ fw3,
                                              const float* __restrict__ fb3,
                                              float* __restrict__ out) {
    int b = blockIdx.x;
    int j = threadIdx.x;
    __shared__ float r[128];
    __shared__ float s1[128];
    r[j] = fc1out[b * 128 + j] + fb1[j];
    __syncthreads();
    float acc = fb2[j];
    for (int i = 0; i < 128; ++i) acc += r[i] * fw2[i * 128 + j];
    s1[j] = acc;
    __syncthreads();
    if (j < 9) {
        float a2 = fb3[j];
        for (int i = 0; i < 128; ++i) a2 += s1[i] * fw3[i * 9 + j];
        out[b * 9 + j] = a2;
    }
}

// ---------------------------------------------------------------------------
extern "C" void kernel_launch(void* const* d_in, const int* in_sizes, int n_in,
                              void* d_out, int out_size, void* d_ws, size_t ws_size,
                              hipStream_t stream) {
    const float* x   = (const float*)d_in[0];
    const int*   src = (const int*)d_in[1];
    const int*   dst = (const int*)d_in[2];
    const float* ew  = (const float*)d_in[3];
    const float* w1  = (const float*)d_in[4];
    const float* b1  = (const float*)d_in[5];
    const float* w2  = (const float*)d_in[6];
    const float* b2  = (const float*)d_in[7];
    const float* w3  = (const float*)d_in[8];
    const float* b3  = (const float*)d_in[9];
    const float* w4  = (const float*)d_in[10];
    const float* b4  = (const float*)d_in[11];
    const float* w5  = (const float*)d_in[12];
    const float* b5  = (const float*)d_in[13];
    const float* fw1 = (const float*)d_in[14];
    const float* fb1 = (const float*)d_in[15];
    const float* fw2 = (const float*)d_in[16];
    const float* fb2 = (const float*)d_in[17];
    const float* fw3 = (const float*)d_in[18];
    const float* fb3 = (const float*)d_in[19];
    float* out = (float*)d_out;

    char* p = (char*)d_ws;
    const size_t XBYTES = (size_t)NN * 2048 * 2;  // 16 MB (bf16)
    ushort_t* X0 = (ushort_t*)(p + 0 * XBYTES);
    ushort_t* X1 = (ushort_t*)(p + 1 * XBYTES);
    ushort_t* X2 = (ushort_t*)(p + 2 * XBYTES);
    ushort_t* X3 = (ushort_t*)(p + 3 * XBYTES);
    size_t off = 4 * XBYTES;
    float* H5     = (float*)(p + off); off += (size_t)NN * 256 * 4;  // fp32
    float* deg    = (float*)(p + off); off += (size_t)NN * 4;
    int*   cnt    = (int*)(p + off);   off += (size_t)NN * 4;
    int*   cursor = (int*)(p + off);   off += (size_t)NN * 4;
    int*   rowptr = (int*)(p + off);   off += (size_t)(NN + 4) * 4;
    int2*  cv     = (int2*)(p + off);  off += (size_t)EPAD * 8;
    float* fc1o   = (float*)(p + off); off += (size_t)BB * 128 * 4;
    float* xn0    = (float*)(p + off); off += (size_t)NN * 64 * 4;
    float* tn1    = (float*)(p + off); off += (size_t)NN * 64 * 4;
    float* tn2    = (float*)(p + off); off += (size_t)NN * 64 * 4;
    float* tn3    = (float*)(p + off); off += (size_t)NN * 64 * 4;
    if (off > ws_size) return;

    hipMemsetAsync(deg, 0, NN * 4, stream);
    hipMemsetAsync(cnt, 0, NN * 4, stream);
    hipMemsetAsync(cv, 0, (size_t)EPAD * 8, stream);
    hipMemsetAsync(fc1o, 0, BB * 128 * 4, stream);

    k_deg_hist<<<EE / 256, 256, 0, stream>>>(src, dst, ew, deg, cnt);
    k_scan<<<1, 1024, 0, stream>>>(cnt, rowptr, cursor);
    k_fill<<<EE / 256, 256, 0, stream>>>(src, dst, ew, deg, cursor, cv);
    k_transpose_x<<<NN / 64, 256, 0, stream>>>(x, xn0);

    // ------------------- layer 1 entirely narrow fp32, then one bf16 expand
    k_spmm_narrow<<<NN, 64, 0, stream>>>(rowptr, cv, xn0, nullptr, tn1, 1.f, 0);
    k_spmm_narrow<<<NN, 64, 0, stream>>>(rowptr, cv, tn1, xn0, tn2, 2.f, 1);
    k_spmm_narrow<<<NN, 64, 0, stream>>>(rowptr, cv, tn2, tn1, tn3, 2.f, 1);
    k_expand1<<<NN, 256, 0, stream>>>(xn0, tn1, tn2, tn3, w1, b1, X3);  // H1 -> X3

    const int GRID = (NN / 4) * 8;
    // ------------------- layers 2-4: S1, S2 pure; S3 fused finalizer
    auto run32 = [&](const ushort_t* H, ushort_t* T1, ushort_t* T2, ushort_t* OUT,
                     const float* W, const float* B) {
        k_spmm_pure<<<GRID, 256, 0, stream>>>(rowptr, cv, H, nullptr, T1);
        k_spmm_pure<<<GRID, 256, 0, stream>>>(rowptr, cv, T1, H, T2);
        k_cheb_out<32, true><<<GRID, 256, 0, stream>>>(rowptr, cv, T2, T1, H, W, B, OUT);
    };
    run32(X3, X0, X1, X2, w2, b2);
    run32(X2, X3, X0, X1, w3, b3);
    run32(X1, X2, X3, X0, w4, b4);

    // ------------------- layer 5 (COUT=4): H=X0 -> H5 fp32 [N][256]
    k_spmm_pure<<<GRID, 256, 0, stream>>>(rowptr, cv, X0, nullptr, X1);
    k_spmm_pure<<<GRID, 256, 0, stream>>>(rowptr, cv, X1, X0, X2);
    k_cheb_out<4, false><<<GRID, 256, 0, stream>>>(rowptr, cv, X2, X1, X0, w5, b5, H5);

    // ------------------- FC head
    k_fc1<<<128, 256, 0, stream>>>(H5, fw1, fc1o);
    k_fc23<<<BB, 128, 0, stream>>>(fc1o, fb1, fw2, fb2, fw3, fb3, out);
}

// Round 8
// 644.137 us; speedup vs baseline: 2.1975x; 1.3424x over previous
//
#include <hip/hip_runtime.h>
#include <cstdint>

#define NN 4096
#define EE 131072
#define BB 64
#define EPAD (EE + 8 * NN)   // CSR rows padded to multiples of 8

typedef float f4 __attribute__((ext_vector_type(4)));
typedef unsigned short ushort_t;
typedef unsigned int uint_t;

// bf16 helpers
__device__ __forceinline__ f4 up4(uint2 u) {
    f4 r;
    r.x = __uint_as_float(u.x << 16);
    r.y = __uint_as_float(u.x & 0xffff0000u);
    r.z = __uint_as_float(u.y << 16);
    r.w = __uint_as_float(u.y & 0xffff0000u);
    return r;
}
__device__ __forceinline__ void up8(uint4 u, f4& lo, f4& hi) {
    lo.x = __uint_as_float(u.x << 16);
    lo.y = __uint_as_float(u.x & 0xffff0000u);
    lo.z = __uint_as_float(u.y << 16);
    lo.w = __uint_as_float(u.y & 0xffff0000u);
    hi.x = __uint_as_float(u.z << 16);
    hi.y = __uint_as_float(u.z & 0xffff0000u);
    hi.z = __uint_as_float(u.w << 16);
    hi.w = __uint_as_float(u.w & 0xffff0000u);
}
__device__ __forceinline__ uint_t bfpk(float a, float b) {
    uint_t xa = __float_as_uint(a); xa = (xa + 0x7fffu + ((xa >> 16) & 1u)) >> 16;
    uint_t xb = __float_as_uint(b); xb = (xb + 0x7fffu + ((xb >> 16) & 1u));
    return (xa & 0xffffu) | (xb & 0xffff0000u);
}

// ---------------------------------------------------------------------------
// Graph preprocessing
// ---------------------------------------------------------------------------
__global__ void k_deg_hist(const int* __restrict__ src, const int* __restrict__ dst,
                           const float* __restrict__ ew, float* __restrict__ deg,
                           int* __restrict__ cnt) {
    int e = blockIdx.x * blockDim.x + threadIdx.x;
    if (e >= EE) return;
    atomicAdd(&deg[src[e]], ew[e]);
    atomicAdd(&cnt[dst[e]], 1);
}

__global__ __launch_bounds__(1024) void k_scan(const int* __restrict__ cnt,
                                               int* __restrict__ rowptr,
                                               int* __restrict__ cursor) {
    __shared__ int s[1024];
    int tid = threadIdx.x;
    int p0 = (cnt[tid * 4 + 0] + 7) & ~7;
    int p1 = (cnt[tid * 4 + 1] + 7) & ~7;
    int p2 = (cnt[tid * 4 + 2] + 7) & ~7;
    int p3 = (cnt[tid * 4 + 3] + 7) & ~7;
    int sum = p0 + p1 + p2 + p3;
    s[tid] = sum;
    __syncthreads();
    for (int off = 1; off < 1024; off <<= 1) {
        int t = (tid >= off) ? s[tid - off] : 0;
        __syncthreads();
        s[tid] += t;
        __syncthreads();
    }
    int excl = s[tid] - sum;
    rowptr[tid * 4 + 0] = excl; cursor[tid * 4 + 0] = excl; excl += p0;
    rowptr[tid * 4 + 1] = excl; cursor[tid * 4 + 1] = excl; excl += p1;
    rowptr[tid * 4 + 2] = excl; cursor[tid * 4 + 2] = excl; excl += p2;
    rowptr[tid * 4 + 3] = excl; cursor[tid * 4 + 3] = excl; excl += p3;
    if (tid == 1023) rowptr[4096] = excl;
}

__global__ void k_fill(const int* __restrict__ src, const int* __restrict__ dst,
                       const float* __restrict__ ew, const float* __restrict__ deg,
                       int* __restrict__ cursor, int2* __restrict__ cv) {
    int e = blockIdx.x * blockDim.x + threadIdx.x;
    if (e >= EE) return;
    int s = src[e], d = dst[e];
    int pos = atomicAdd(&cursor[d], 1);
    float ds = deg[s], dd = deg[d];
    float is = ds > 0.f ? rsqrtf(fmaxf(ds, 1e-30f)) : 0.f;
    float id = dd > 0.f ? rsqrtf(fmaxf(dd, 1e-30f)) : 0.f;
    float v = -(is * ew[e] * id);
    cv[pos] = make_int2(s, __float_as_int(v));
}

// ---------------------------------------------------------------------------
// Transpose x [B,N] -> X0 [N,B]  (fp32, layer-1 narrow path)
// ---------------------------------------------------------------------------
__global__ __launch_bounds__(256) void k_transpose_x(const float* __restrict__ x,
                                                     float* __restrict__ X0) {
    __shared__ float s[64 * 65];
    int n0 = blockIdx.x * 64;
    for (int idx = threadIdx.x; idx < 4096; idx += 256) {
        int b = idx >> 6, nl = idx & 63;
        s[nl * 65 + b] = x[(size_t)b * NN + n0 + nl];
    }
    __syncthreads();
    for (int idx = threadIdx.x; idx < 4096; idx += 256) {
        int nl = idx >> 6, b = idx & 63;
        X0[(size_t)(n0 + nl) * 64 + b] = s[nl * 65 + b];
    }
}

// ---------------------------------------------------------------------------
// SpMM narrow (width 64, fp32, layer 1), tail-free x8 gather loop
// ---------------------------------------------------------------------------
__global__ __launch_bounds__(64) void k_spmm_narrow(const int* __restrict__ rowptr,
                                                    const int2* __restrict__ cv,
                                                    const float* __restrict__ Zin,
                                                    const float* __restrict__ Tprev,
                                                    float* __restrict__ Tout,
                                                    float alpha, int useprev) {
    int n = blockIdx.x;
    int lane = threadIdx.x;
    int start = rowptr[n], end = rowptr[n + 1];
    float acc = 0.f;
    for (int e = start; e < end; e += 8) {
        const int4* q = reinterpret_cast<const int4*>(cv + e);
        int4 a = q[0], b = q[1], c = q[2], d = q[3];
        float z0 = Zin[((size_t)a.x << 6) + lane];
        float z1 = Zin[((size_t)a.z << 6) + lane];
        float z2 = Zin[((size_t)b.x << 6) + lane];
        float z3 = Zin[((size_t)b.z << 6) + lane];
        float z4 = Zin[((size_t)c.x << 6) + lane];
        float z5 = Zin[((size_t)c.z << 6) + lane];
        float z6 = Zin[((size_t)d.x << 6) + lane];
        float z7 = Zin[((size_t)d.z << 6) + lane];
        acc += __int_as_float(a.y) * z0 + __int_as_float(a.w) * z1
             + __int_as_float(b.y) * z2 + __int_as_float(b.w) * z3
             + __int_as_float(c.y) * z4 + __int_as_float(c.w) * z5
             + __int_as_float(d.y) * z6 + __int_as_float(d.w) * z7;
    }
    size_t o = ((size_t)n << 6) + lane;
    float r = alpha * acc;
    if (useprev) r -= Tprev[o];
    Tout[o] = r;
}

// ---------------------------------------------------------------------------
// Layer-1 expand -> bf16 H
// ---------------------------------------------------------------------------
__global__ __launch_bounds__(256) void k_expand1(const float* __restrict__ T0,
                                                 const float* __restrict__ T1,
                                                 const float* __restrict__ T2,
                                                 const float* __restrict__ T3,
                                                 const float* __restrict__ w1,
                                                 const float* __restrict__ b1,
                                                 ushort_t* __restrict__ H) {
    __shared__ float sT[4][64];
    __shared__ float sW[128];
    __shared__ float sB[32];
    int n = blockIdx.x, tid = threadIdx.x;
    {
        int k = tid >> 6, b = tid & 63;
        const float* Tk = (k == 0) ? T0 : (k == 1) ? T1 : (k == 2) ? T2 : T3;
        sT[k][b] = Tk[(size_t)n * 64 + b];
    }
    if (tid < 128) sW[tid] = w1[tid];
    if (tid < 32) sB[tid] = b1[tid];
    __syncthreads();
    int col0 = tid * 8;
    int b = tid >> 2;
    int co0 = col0 & 31;
    float t0 = sT[0][b], t1 = sT[1][b], t2 = sT[2][b], t3 = sT[3][b];
    float r[8];
#pragma unroll
    for (int j = 0; j < 8; ++j) {
        int co = co0 + j;
        float v = t0 * sW[co] + t1 * sW[32 + co] + t2 * sW[64 + co] + t3 * sW[96 + co] + sB[co];
        r[j] = v > 0.f ? v : 0.f;
    }
    uint4 st;
    st.x = bfpk(r[0], r[1]); st.y = bfpk(r[2], r[3]);
    st.z = bfpk(r[4], r[5]); st.w = bfpk(r[6], r[7]);
    *reinterpret_cast<uint4*>(H + (size_t)n * 2048 + col0) = st;
}

// ---------------------------------------------------------------------------
// Pure wide SpMM (bf16, fp32 accumulate), 4 chunks x 512 cols, 16B gathers.
//   Tout = (Pown ? 2*(L@Zg) - Pown : L@Zg)
// chunk = blockIdx & 3 -> XCDs {c, c+4} each cache one 4MB slice.
// ---------------------------------------------------------------------------
__global__ __launch_bounds__(256) void k_spmm_pure(const int* __restrict__ rowptr,
                                                   const int2* __restrict__ cv,
                                                   const ushort_t* __restrict__ Zg,
                                                   const ushort_t* __restrict__ Pown,
                                                   ushort_t* __restrict__ Tout) {
    int chunk = blockIdx.x & 3;
    int rowblk = blockIdx.x >> 2;
    int wave = threadIdx.x >> 6;
    int lane = threadIdx.x & 63;
    int n = rowblk * 4 + wave;
    int col0 = chunk * 512 + lane * 8;

    int start = rowptr[n], end = rowptr[n + 1];
    f4 aL0 = {0,0,0,0}, aH0 = {0,0,0,0}, aL1 = {0,0,0,0}, aH1 = {0,0,0,0};
    for (int e = start; e < end; e += 8) {
        const int4* q = reinterpret_cast<const int4*>(cv + e);
        int4 a = q[0], b = q[1], c = q[2], d = q[3];
        uint4 u0 = *reinterpret_cast<const uint4*>(Zg + (((size_t)a.x) << 11) + col0);
        uint4 u1 = *reinterpret_cast<const uint4*>(Zg + (((size_t)a.z) << 11) + col0);
        uint4 u2 = *reinterpret_cast<const uint4*>(Zg + (((size_t)b.x) << 11) + col0);
        uint4 u3 = *reinterpret_cast<const uint4*>(Zg + (((size_t)b.z) << 11) + col0);
        uint4 u4 = *reinterpret_cast<const uint4*>(Zg + (((size_t)c.x) << 11) + col0);
        uint4 u5 = *reinterpret_cast<const uint4*>(Zg + (((size_t)c.z) << 11) + col0);
        uint4 u6 = *reinterpret_cast<const uint4*>(Zg + (((size_t)d.x) << 11) + col0);
        uint4 u7 = *reinterpret_cast<const uint4*>(Zg + (((size_t)d.z) << 11) + col0);
        f4 lo, hi;
        up8(u0, lo, hi); aL0 += __int_as_float(a.y) * lo; aH0 += __int_as_float(a.y) * hi;
        up8(u1, lo, hi); aL1 += __int_as_float(a.w) * lo; aH1 += __int_as_float(a.w) * hi;
        up8(u2, lo, hi); aL0 += __int_as_float(b.y) * lo; aH0 += __int_as_float(b.y) * hi;
        up8(u3, lo, hi); aL1 += __int_as_float(b.w) * lo; aH1 += __int_as_float(b.w) * hi;
        up8(u4, lo, hi); aL0 += __int_as_float(c.y) * lo; aH0 += __int_as_float(c.y) * hi;
        up8(u5, lo, hi); aL1 += __int_as_float(c.w) * lo; aH1 += __int_as_float(c.w) * hi;
        up8(u6, lo, hi); aL0 += __int_as_float(d.y) * lo; aH0 += __int_as_float(d.y) * hi;
        up8(u7, lo, hi); aL1 += __int_as_float(d.w) * lo; aH1 += __int_as_float(d.w) * hi;
    }
    size_t o = (((size_t)n) << 11) + col0;
    f4 tL = aL0 + aL1, tH = aH0 + aH1;
    if (Pown) {
        uint4 pu = *reinterpret_cast<const uint4*>(Pown + o);
        f4 pL, pH;
        up8(pu, pL, pH);
        tL = 2.f * tL - pL;
        tH = 2.f * tH - pH;
    }
    uint4 st;
    st.x = bfpk(tL.x, tL.y); st.y = bfpk(tL.z, tL.w);
    st.z = bfpk(tH.x, tH.y); st.w = bfpk(tH.z, tH.w);
    *reinterpret_cast<uint4*>(Tout + o) = st;
}

// ---------------------------------------------------------------------------
// Chebyshev finalizer (bf16 storage, 4 chunks x 512 cols):
//   T3 = 2*(L@T2g) - T1  (fp32 in-register)
//   OUT = relu( H*W0 + T1*W1 + T2*W2 + T3*W3 + bias )
// Planes staged in LDS as packed bf16 (stride 20 uints, 16B aligned).
// ---------------------------------------------------------------------------
template <int COUT, bool OUTBF>
__global__ __launch_bounds__(256, 4) void k_cheb_out(
    const int* __restrict__ rowptr, const int2* __restrict__ cv,
    const ushort_t* __restrict__ T2g,  // gather source (T2), also own-row read
    const ushort_t* __restrict__ T1,   // own-row: Pown + W1 operand
    const ushort_t* __restrict__ H,    // own-row: W0 operand
    const float* __restrict__ W,       // [4*32*COUT] planes {W0,W1,W2,W3}
    const float* __restrict__ bias,    // [COUT]
    void* __restrict__ OUTv)
{
    __shared__ float sW[4 * 32 * COUT];
    __shared__ uint_t sPu[4][4][320];  // [wave][plane H,T1,T2,T3][16 batches x 20]

    int chunk = blockIdx.x & 3;
    int rowblk = blockIdx.x >> 2;
    int wave = threadIdx.x >> 6;
    int lane = threadIdx.x & 63;
    int n = rowblk * 4 + wave;
    int col0 = chunk * 512 + lane * 8;
    int tid = threadIdx.x;

    for (int idx = tid; idx < 4 * 32 * COUT; idx += 256) sW[idx] = W[idx];

    int start = rowptr[n], end = rowptr[n + 1];
    f4 aL0 = {0,0,0,0}, aH0 = {0,0,0,0}, aL1 = {0,0,0,0}, aH1 = {0,0,0,0};
    for (int e = start; e < end; e += 8) {
        const int4* q = reinterpret_cast<const int4*>(cv + e);
        int4 a = q[0], b = q[1], c = q[2], d = q[3];
        uint4 u0 = *reinterpret_cast<const uint4*>(T2g + (((size_t)a.x) << 11) + col0);
        uint4 u1 = *reinterpret_cast<const uint4*>(T2g + (((size_t)a.z) << 11) + col0);
        uint4 u2 = *reinterpret_cast<const uint4*>(T2g + (((size_t)b.x) << 11) + col0);
        uint4 u3 = *reinterpret_cast<const uint4*>(T2g + (((size_t)b.z) << 11) + col0);
        uint4 u4 = *reinterpret_cast<const uint4*>(T2g + (((size_t)c.x) << 11) + col0);
        uint4 u5 = *reinterpret_cast<const uint4*>(T2g + (((size_t)c.z) << 11) + col0);
        uint4 u6 = *reinterpret_cast<const uint4*>(T2g + (((size_t)d.x) << 11) + col0);
        uint4 u7 = *reinterpret_cast<const uint4*>(T2g + (((size_t)d.z) << 11) + col0);
        f4 lo, hi;
        up8(u0, lo, hi); aL0 += __int_as_float(a.y) * lo; aH0 += __int_as_float(a.y) * hi;
        up8(u1, lo, hi); aL1 += __int_as_float(a.w) * lo; aH1 += __int_as_float(a.w) * hi;
        up8(u2, lo, hi); aL0 += __int_as_float(b.y) * lo; aH0 += __int_as_float(b.y) * hi;
        up8(u3, lo, hi); aL1 += __int_as_float(b.w) * lo; aH1 += __int_as_float(b.w) * hi;
        up8(u4, lo, hi); aL0 += __int_as_float(c.y) * lo; aH0 += __int_as_float(c.y) * hi;
        up8(u5, lo, hi); aL1 += __int_as_float(c.w) * lo; aH1 += __int_as_float(c.w) * hi;
        up8(u6, lo, hi); aL0 += __int_as_float(d.y) * lo; aH0 += __int_as_float(d.y) * hi;
        up8(u7, lo, hi); aL1 += __int_as_float(d.w) * lo; aH1 += __int_as_float(d.w) * hi;
    }
    size_t o = (((size_t)n) << 11) + col0;

    int g = lane >> 2, qd = lane & 3;        // batch-in-chunk, uint-quad
    int si = g * 20 + qd * 4;
    {   // T3 = 2*U - T1own ; store T3 (plane 3) and T1 (plane 1) packed
        uint4 pu = *reinterpret_cast<const uint4*>(T1 + o);
        f4 pL, pH;
        up8(pu, pL, pH);
        f4 tL = 2.f * (aL0 + aL1) - pL;
        f4 tH = 2.f * (aH0 + aH1) - pH;
        uint4 st;
        st.x = bfpk(tL.x, tL.y); st.y = bfpk(tL.z, tL.w);
        st.z = bfpk(tH.x, tH.y); st.w = bfpk(tH.z, tH.w);
        *reinterpret_cast<uint4*>(&sPu[wave][3][si]) = st;
        *reinterpret_cast<uint4*>(&sPu[wave][1][si]) = pu;
    }
    *reinterpret_cast<uint4*>(&sPu[wave][2][si]) =
        *reinterpret_cast<const uint4*>(T2g + o);
    *reinterpret_cast<uint4*>(&sPu[wave][0][si]) =
        *reinterpret_cast<const uint4*>(H + o);
    __syncthreads();

    if constexpr (COUT == 32) {
        int co0 = qd * 8;
        f4 oacc0 = {0,0,0,0}, oacc1 = {0,0,0,0};
#pragma unroll
        for (int u = 0; u < 16; ++u) {
#pragma unroll
            for (int p = 0; p < 4; ++p) {
                uint_t au = sPu[wave][p][g * 20 + u];
                float alo = __uint_as_float(au << 16);
                float ahi = __uint_as_float(au & 0xffff0000u);
                const float* wr0 = &sW[p * 1024 + (2 * u) * 32 + co0];
                const float* wr1 = &sW[p * 1024 + (2 * u + 1) * 32 + co0];
                oacc0 += alo * *reinterpret_cast<const f4*>(wr0);
                oacc1 += alo * *reinterpret_cast<const f4*>(wr0 + 4);
                oacc0 += ahi * *reinterpret_cast<const f4*>(wr1);
                oacc1 += ahi * *reinterpret_cast<const f4*>(wr1 + 4);
            }
        }
        f4 r0, r1;
        r0.x = oacc0.x + bias[co0 + 0]; r0.y = oacc0.y + bias[co0 + 1];
        r0.z = oacc0.z + bias[co0 + 2]; r0.w = oacc0.w + bias[co0 + 3];
        r1.x = oacc1.x + bias[co0 + 4]; r1.y = oacc1.y + bias[co0 + 5];
        r1.z = oacc1.z + bias[co0 + 6]; r1.w = oacc1.w + bias[co0 + 7];
        r0.x = r0.x > 0.f ? r0.x : 0.f; r0.y = r0.y > 0.f ? r0.y : 0.f;
        r0.z = r0.z > 0.f ? r0.z : 0.f; r0.w = r0.w > 0.f ? r0.w : 0.f;
        r1.x = r1.x > 0.f ? r1.x : 0.f; r1.y = r1.y > 0.f ? r1.y : 0.f;
        r1.z = r1.z > 0.f ? r1.z : 0.f; r1.w = r1.w > 0.f ? r1.w : 0.f;
        if constexpr (OUTBF) {
            uint4 st;
            st.x = bfpk(r0.x, r0.y); st.y = bfpk(r0.z, r0.w);
            st.z = bfpk(r1.x, r1.y); st.w = bfpk(r1.z, r1.w);
            *reinterpret_cast<uint4*>((ushort_t*)OUTv + o) = st;
        } else {
            float* po = (float*)OUTv + o;
            *reinterpret_cast<f4*>(po) = r0;
            *reinterpret_cast<f4*>(po + 4) = r1;
        }
    } else {  // COUT == 4: one output per lane; col = b*4+co
        int co = lane & 3;
        float o0 = 0.f;
#pragma unroll
        for (int u = 0; u < 16; ++u) {
#pragma unroll
            for (int p = 0; p < 4; ++p) {
                uint_t au = sPu[wave][p][g * 20 + u];
                float alo = __uint_as_float(au << 16);
                float ahi = __uint_as_float(au & 0xffff0000u);
                o0 += alo * sW[p * 128 + (2 * u) * 4 + co]
                    + ahi * sW[p * 128 + (2 * u + 1) * 4 + co];
            }
        }
        float r = o0 + bias[co];
        r = r > 0.f ? r : 0.f;
        ((float*)OUTv)[n * 256 + chunk * 64 + lane] = r;
    }
}

// ---------------------------------------------------------------------------
// FC1: split-K over 128 blocks, atomic accumulate. h[b, n*4+c] = H5[n, b*4+c]
// ---------------------------------------------------------------------------
__global__ __launch_bounds__(256) void k_fc1(const float* __restrict__ H5,
                                             const float* __restrict__ fw1,
                                             float* __restrict__ fc1out) {
    __shared__ float hT[128 * 65];
    __shared__ float wS[32 * 128];
    int tid = threadIdx.x;
    int n0 = blockIdx.x * 32;
    for (int idx = tid; idx < 8192; idx += 256) {
        int n_l = idx >> 8;
        int rem = idx & 255;
        int b = rem >> 2, c = rem & 3;
        int kk = n_l * 4 + c;
        hT[kk * 65 + b] = H5[(size_t)(n0 + n_l) * 256 + rem];
    }
    float acc[8][4];
#pragma unroll
    for (int i = 0; i < 8; ++i)
#pragma unroll
        for (int j = 0; j < 4; ++j) acc[i][j] = 0.f;
    int bq = tid >> 5;
    int jq = tid & 31;
    for (int kb = 0; kb < 128; kb += 32) {
        __syncthreads();
        for (int idx = tid; idx < 4096; idx += 256) {
            int kl = idx >> 7, j = idx & 127;
            wS[idx] = fw1[(size_t)(n0 * 4 + kb + kl) * 128 + j];
        }
        __syncthreads();
        for (int kl = 0; kl < 32; ++kl) {
            int kk = kb + kl;
            float4 w = *reinterpret_cast<const float4*>(&wS[kl * 128 + jq * 4]);
#pragma unroll
            for (int bi = 0; bi < 8; ++bi) {
                float h = hT[kk * 65 + bq * 8 + bi];
                acc[bi][0] += h * w.x;
                acc[bi][1] += h * w.y;
                acc[bi][2] += h * w.z;
                acc[bi][3] += h * w.w;
            }
        }
    }
#pragma unroll
    for (int bi = 0; bi < 8; ++bi)
#pragma unroll
        for (int ji = 0; ji < 4; ++ji)
            atomicAdd(&fc1out[(bq * 8 + bi) * 128 + jq * 4 + ji], acc[bi][ji]);
}

__global__ __launch_bounds__(128) void k_fc23(const float* __restrict__ fc1out,
                                              const float* __restrict__ fb1,
                                              const float* __restrict__ fw2,
                                              const float* __restrict__ fb2,
                                              const float* __restrict__ fw3,
                                              const float* __restrict__ fb3,
                                              float* __restrict__ out) {
    int b = blockIdx.x;
    int j = threadIdx.x;
    __shared__ float r[128];
    __shared__ float s1[128];
    r[j] = fc1out[b * 128 + j] + fb1[j];
    __syncthreads();
    float acc = fb2[j];
    for (int i = 0; i < 128; ++i) acc += r[i] * fw2[i * 128 + j];
    s1[j] = acc;
    __syncthreads();
    if (j < 9) {
        float a2 = fb3[j];
        for (int i = 0; i < 128; ++i) a2 += s1[i] * fw3[i * 9 + j];
        out[b * 9 + j] = a2;
    }
}

// ---------------------------------------------------------------------------
extern "C" void kernel_launch(void* const* d_in, const int* in_sizes, int n_in,
                              void* d_out, int out_size, void* d_ws, size_t ws_size,
                              hipStream_t stream) {
    const float* x   = (const float*)d_in[0];
    const int*   src = (const int*)d_in[1];
    const int*   dst = (const int*)d_in[2];
    const float* ew  = (const float*)d_in[3];
    const float* w1  = (const float*)d_in[4];
    const float* b1  = (const float*)d_in[5];
    const float* w2  = (const float*)d_in[6];
    const float* b2  = (const float*)d_in[7];
    const float* w3  = (const float*)d_in[8];
    const float* b3  = (const float*)d_in[9];
    const float* w4  = (const float*)d_in[10];
    const float* b4  = (const float*)d_in[11];
    const float* w5  = (const float*)d_in[12];
    const float* b5  = (const float*)d_in[13];
    const float* fw1 = (const float*)d_in[14];
    const float* fb1 = (const float*)d_in[15];
    const float* fw2 = (const float*)d_in[16];
    const float* fb2 = (const float*)d_in[17];
    const float* fw3 = (const float*)d_in[18];
    const float* fb3 = (const float*)d_in[19];
    float* out = (float*)d_out;

    char* p = (char*)d_ws;
    const size_t XBYTES = (size_t)NN * 2048 * 2;  // 16 MB (bf16)
    ushort_t* X0 = (ushort_t*)(p + 0 * XBYTES);
    ushort_t* X1 = (ushort_t*)(p + 1 * XBYTES);
    ushort_t* X2 = (ushort_t*)(p + 2 * XBYTES);
    ushort_t* X3 = (ushort_t*)(p + 3 * XBYTES);
    size_t off = 4 * XBYTES;
    float* H5     = (float*)(p + off); off += (size_t)NN * 256 * 4;  // fp32
    float* deg    = (float*)(p + off); off += (size_t)NN * 4;
    int*   cnt    = (int*)(p + off);   off += (size_t)NN * 4;
    int*   cursor = (int*)(p + off);   off += (size_t)NN * 4;
    int*   rowptr = (int*)(p + off);   off += (size_t)(NN + 4) * 4;
    int2*  cv     = (int2*)(p + off);  off += (size_t)EPAD * 8;
    float* fc1o   = (float*)(p + off); off += (size_t)BB * 128 * 4;
    float* xn0    = (float*)(p + off); off += (size_t)NN * 64 * 4;
    float* tn1    = (float*)(p + off); off += (size_t)NN * 64 * 4;
    float* tn2    = (float*)(p + off); off += (size_t)NN * 64 * 4;
    float* tn3    = (float*)(p + off); off += (size_t)NN * 64 * 4;
    if (off > ws_size) return;

    hipMemsetAsync(deg, 0, NN * 4, stream);
    hipMemsetAsync(cnt, 0, NN * 4, stream);
    hipMemsetAsync(cv, 0, (size_t)EPAD * 8, stream);
    hipMemsetAsync(fc1o, 0, BB * 128 * 4, stream);

    k_deg_hist<<<EE / 256, 256, 0, stream>>>(src, dst, ew, deg, cnt);
    k_scan<<<1, 1024, 0, stream>>>(cnt, rowptr, cursor);
    k_fill<<<EE / 256, 256, 0, stream>>>(src, dst, ew, deg, cursor, cv);
    k_transpose_x<<<NN / 64, 256, 0, stream>>>(x, xn0);

    // ------------------- layer 1 entirely narrow fp32, then one bf16 expand
    k_spmm_narrow<<<NN, 64, 0, stream>>>(rowptr, cv, xn0, nullptr, tn1, 1.f, 0);
    k_spmm_narrow<<<NN, 64, 0, stream>>>(rowptr, cv, tn1, xn0, tn2, 2.f, 1);
    k_spmm_narrow<<<NN, 64, 0, stream>>>(rowptr, cv, tn2, tn1, tn3, 2.f, 1);
    k_expand1<<<NN, 256, 0, stream>>>(xn0, tn1, tn2, tn3, w1, b1, X3);  // H1 -> X3

    const int GRID4 = (NN / 4) * 4;   // 4096 blocks: 4 chunks x 512 cols
    // ------------------- layers 2-4: S1, S2 pure; S3 fused finalizer
    auto run32 = [&](const ushort_t* H, ushort_t* T1, ushort_t* T2, ushort_t* OUT,
                     const float* W, const float* B) {
        k_spmm_pure<<<GRID4, 256, 0, stream>>>(rowptr, cv, H, nullptr, T1);
        k_spmm_pure<<<GRID4, 256, 0, stream>>>(rowptr, cv, T1, H, T2);
        k_cheb_out<32, true><<<GRID4, 256, 0, stream>>>(rowptr, cv, T2, T1, H, W, B, OUT);
    };
    run32(X3, X0, X1, X2, w2, b2);
    run32(X2, X3, X0, X1, w3, b3);
    run32(X1, X2, X3, X0, w4, b4);

    // ------------------- layer 5 (COUT=4): H=X0 -> H5 fp32 [N][256]
    k_spmm_pure<<<GRID4, 256, 0, stream>>>(rowptr, cv, X0, nullptr, X1);
    k_spmm_pure<<<GRID4, 256, 0, stream>>>(rowptr, cv, X1, X0, X2);
    k_cheb_out<4, false><<<GRID4, 256, 0, stream>>>(rowptr, cv, X2, X1, X0, w5, b5, H5);

    // ------------------- FC head
    k_fc1<<<128, 256, 0, stream>>>(H5, fw1, fc1o);
    k_fc23<<<BB, 128, 0, stream>>>(fc1o, fb1, fw2, fb2, fw3, fb3, out);
}

// Round 9
// 641.111 us; speedup vs baseline: 2.2078x; 1.0047x over previous
//
#include <hip/hip_runtime.h>
#include <cstdint>

#define NN 4096
#define EE 131072
#define BB 64
#define EPAD (EE + 8 * NN)   // CSR rows padded to multiples of 8

typedef float f4 __attribute__((ext_vector_type(4)));
typedef short bf16x8 __attribute__((ext_vector_type(8)));
typedef unsigned short ushort_t;
typedef unsigned int uint_t;

// bf16 helpers
__device__ __forceinline__ void up8(uint4 u, f4& lo, f4& hi) {
    lo.x = __uint_as_float(u.x << 16);
    lo.y = __uint_as_float(u.x & 0xffff0000u);
    lo.z = __uint_as_float(u.y << 16);
    lo.w = __uint_as_float(u.y & 0xffff0000u);
    hi.x = __uint_as_float(u.z << 16);
    hi.y = __uint_as_float(u.z & 0xffff0000u);
    hi.z = __uint_as_float(u.w << 16);
    hi.w = __uint_as_float(u.w & 0xffff0000u);
}
__device__ __forceinline__ uint_t bfpk(float a, float b) {
    uint_t xa = __float_as_uint(a); xa = (xa + 0x7fffu + ((xa >> 16) & 1u)) >> 16;
    uint_t xb = __float_as_uint(b); xb = (xb + 0x7fffu + ((xb >> 16) & 1u));
    return (xa & 0xffffu) | (xb & 0xffff0000u);
}
__device__ __forceinline__ ushort_t bf1(float a) {
    uint_t x = __float_as_uint(a);
    return (ushort_t)((x + 0x7fffu + ((x >> 16) & 1u)) >> 16);
}

// ---------------------------------------------------------------------------
// Graph preprocessing
// ---------------------------------------------------------------------------
__global__ void k_deg_hist(const int* __restrict__ src, const int* __restrict__ dst,
                           const float* __restrict__ ew, float* __restrict__ deg,
                           int* __restrict__ cnt) {
    int e = blockIdx.x * blockDim.x + threadIdx.x;
    if (e >= EE) return;
    atomicAdd(&deg[src[e]], ew[e]);
    atomicAdd(&cnt[dst[e]], 1);
}

__global__ __launch_bounds__(1024) void k_scan(const int* __restrict__ cnt,
                                               int* __restrict__ rowptr,
                                               int* __restrict__ cursor) {
    __shared__ int s[1024];
    int tid = threadIdx.x;
    int p0 = (cnt[tid * 4 + 0] + 7) & ~7;
    int p1 = (cnt[tid * 4 + 1] + 7) & ~7;
    int p2 = (cnt[tid * 4 + 2] + 7) & ~7;
    int p3 = (cnt[tid * 4 + 3] + 7) & ~7;
    int sum = p0 + p1 + p2 + p3;
    s[tid] = sum;
    __syncthreads();
    for (int off = 1; off < 1024; off <<= 1) {
        int t = (tid >= off) ? s[tid - off] : 0;
        __syncthreads();
        s[tid] += t;
        __syncthreads();
    }
    int excl = s[tid] - sum;
    rowptr[tid * 4 + 0] = excl; cursor[tid * 4 + 0] = excl; excl += p0;
    rowptr[tid * 4 + 1] = excl; cursor[tid * 4 + 1] = excl; excl += p1;
    rowptr[tid * 4 + 2] = excl; cursor[tid * 4 + 2] = excl; excl += p2;
    rowptr[tid * 4 + 3] = excl; cursor[tid * 4 + 3] = excl; excl += p3;
    if (tid == 1023) rowptr[4096] = excl;
}

__global__ void k_fill(const int* __restrict__ src, const int* __restrict__ dst,
                       const float* __restrict__ ew, const float* __restrict__ deg,
                       int* __restrict__ cursor, int2* __restrict__ cv) {
    int e = blockIdx.x * blockDim.x + threadIdx.x;
    if (e >= EE) return;
    int s = src[e], d = dst[e];
    int pos = atomicAdd(&cursor[d], 1);
    float ds = deg[s], dd = deg[d];
    float is = ds > 0.f ? rsqrtf(fmaxf(ds, 1e-30f)) : 0.f;
    float id = dd > 0.f ? rsqrtf(fmaxf(dd, 1e-30f)) : 0.f;
    float v = -(is * ew[e] * id);
    cv[pos] = make_int2(s, __float_as_int(v));
}

// ---------------------------------------------------------------------------
// Transpose x [B,N] -> X0 [N,B]  (fp32, layer-1 narrow path)
// ---------------------------------------------------------------------------
__global__ __launch_bounds__(256) void k_transpose_x(const float* __restrict__ x,
                                                     float* __restrict__ X0) {
    __shared__ float s[64 * 65];
    int n0 = blockIdx.x * 64;
    for (int idx = threadIdx.x; idx < 4096; idx += 256) {
        int b = idx >> 6, nl = idx & 63;
        s[nl * 65 + b] = x[(size_t)b * NN + n0 + nl];
    }
    __syncthreads();
    for (int idx = threadIdx.x; idx < 4096; idx += 256) {
        int nl = idx >> 6, b = idx & 63;
        X0[(size_t)(n0 + nl) * 64 + b] = s[nl * 65 + b];
    }
}

// ---------------------------------------------------------------------------
// SpMM narrow (width 64, fp32, layer 1), tail-free x8 gather loop
// ---------------------------------------------------------------------------
__global__ __launch_bounds__(64) void k_spmm_narrow(const int* __restrict__ rowptr,
                                                    const int2* __restrict__ cv,
                                                    const float* __restrict__ Zin,
                                                    const float* __restrict__ Tprev,
                                                    float* __restrict__ Tout,
                                                    float alpha, int useprev) {
    int n = blockIdx.x;
    int lane = threadIdx.x;
    int start = rowptr[n], end = rowptr[n + 1];
    float acc = 0.f;
    for (int e = start; e < end; e += 8) {
        const int4* q = reinterpret_cast<const int4*>(cv + e);
        int4 a = q[0], b = q[1], c = q[2], d = q[3];
        float z0 = Zin[((size_t)a.x << 6) + lane];
        float z1 = Zin[((size_t)a.z << 6) + lane];
        float z2 = Zin[((size_t)b.x << 6) + lane];
        float z3 = Zin[((size_t)b.z << 6) + lane];
        float z4 = Zin[((size_t)c.x << 6) + lane];
        float z5 = Zin[((size_t)c.z << 6) + lane];
        float z6 = Zin[((size_t)d.x << 6) + lane];
        float z7 = Zin[((size_t)d.z << 6) + lane];
        acc += __int_as_float(a.y) * z0 + __int_as_float(a.w) * z1
             + __int_as_float(b.y) * z2 + __int_as_float(b.w) * z3
             + __int_as_float(c.y) * z4 + __int_as_float(c.w) * z5
             + __int_as_float(d.y) * z6 + __int_as_float(d.w) * z7;
    }
    size_t o = ((size_t)n << 6) + lane;
    float r = alpha * acc;
    if (useprev) r -= Tprev[o];
    Tout[o] = r;
}

// ---------------------------------------------------------------------------
// Layer-1 expand -> bf16 H
// ---------------------------------------------------------------------------
__global__ __launch_bounds__(256) void k_expand1(const float* __restrict__ T0,
                                                 const float* __restrict__ T1,
                                                 const float* __restrict__ T2,
                                                 const float* __restrict__ T3,
                                                 const float* __restrict__ w1,
                                                 const float* __restrict__ b1,
                                                 ushort_t* __restrict__ H) {
    __shared__ float sT[4][64];
    __shared__ float sW[128];
    __shared__ float sB[32];
    int n = blockIdx.x, tid = threadIdx.x;
    {
        int k = tid >> 6, b = tid & 63;
        const float* Tk = (k == 0) ? T0 : (k == 1) ? T1 : (k == 2) ? T2 : T3;
        sT[k][b] = Tk[(size_t)n * 64 + b];
    }
    if (tid < 128) sW[tid] = w1[tid];
    if (tid < 32) sB[tid] = b1[tid];
    __syncthreads();
    int col0 = tid * 8;
    int b = tid >> 2;
    int co0 = col0 & 31;
    float t0 = sT[0][b], t1 = sT[1][b], t2 = sT[2][b], t3 = sT[3][b];
    float r[8];
#pragma unroll
    for (int j = 0; j < 8; ++j) {
        int co = co0 + j;
        float v = t0 * sW[co] + t1 * sW[32 + co] + t2 * sW[64 + co] + t3 * sW[96 + co] + sB[co];
        r[j] = v > 0.f ? v : 0.f;
    }
    uint4 st;
    st.x = bfpk(r[0], r[1]); st.y = bfpk(r[2], r[3]);
    st.z = bfpk(r[4], r[5]); st.w = bfpk(r[6], r[7]);
    *reinterpret_cast<uint4*>(H + (size_t)n * 2048 + col0) = st;
}

// ---------------------------------------------------------------------------
// Pure wide SpMM (bf16, fp32 accumulate), 4 chunks x 512 cols, 16B gathers.
// ---------------------------------------------------------------------------
__global__ __launch_bounds__(256) void k_spmm_pure(const int* __restrict__ rowptr,
                                                   const int2* __restrict__ cv,
                                                   const ushort_t* __restrict__ Zg,
                                                   const ushort_t* __restrict__ Pown,
                                                   ushort_t* __restrict__ Tout) {
    int chunk = blockIdx.x & 3;
    int rowblk = blockIdx.x >> 2;
    int wave = threadIdx.x >> 6;
    int lane = threadIdx.x & 63;
    int n = rowblk * 4 + wave;
    int col0 = chunk * 512 + lane * 8;

    int start = rowptr[n], end = rowptr[n + 1];
    f4 aL0 = {0,0,0,0}, aH0 = {0,0,0,0}, aL1 = {0,0,0,0}, aH1 = {0,0,0,0};
    for (int e = start; e < end; e += 8) {
        const int4* q = reinterpret_cast<const int4*>(cv + e);
        int4 a = q[0], b = q[1], c = q[2], d = q[3];
        uint4 u0 = *reinterpret_cast<const uint4*>(Zg + (((size_t)a.x) << 11) + col0);
        uint4 u1 = *reinterpret_cast<const uint4*>(Zg + (((size_t)a.z) << 11) + col0);
        uint4 u2 = *reinterpret_cast<const uint4*>(Zg + (((size_t)b.x) << 11) + col0);
        uint4 u3 = *reinterpret_cast<const uint4*>(Zg + (((size_t)b.z) << 11) + col0);
        uint4 u4 = *reinterpret_cast<const uint4*>(Zg + (((size_t)c.x) << 11) + col0);
        uint4 u5 = *reinterpret_cast<const uint4*>(Zg + (((size_t)c.z) << 11) + col0);
        uint4 u6 = *reinterpret_cast<const uint4*>(Zg + (((size_t)d.x) << 11) + col0);
        uint4 u7 = *reinterpret_cast<const uint4*>(Zg + (((size_t)d.z) << 11) + col0);
        f4 lo, hi;
        up8(u0, lo, hi); aL0 += __int_as_float(a.y) * lo; aH0 += __int_as_float(a.y) * hi;
        up8(u1, lo, hi); aL1 += __int_as_float(a.w) * lo; aH1 += __int_as_float(a.w) * hi;
        up8(u2, lo, hi); aL0 += __int_as_float(b.y) * lo; aH0 += __int_as_float(b.y) * hi;
        up8(u3, lo, hi); aL1 += __int_as_float(b.w) * lo; aH1 += __int_as_float(b.w) * hi;
        up8(u4, lo, hi); aL0 += __int_as_float(c.y) * lo; aH0 += __int_as_float(c.y) * hi;
        up8(u5, lo, hi); aL1 += __int_as_float(c.w) * lo; aH1 += __int_as_float(c.w) * hi;
        up8(u6, lo, hi); aL0 += __int_as_float(d.y) * lo; aH0 += __int_as_float(d.y) * hi;
        up8(u7, lo, hi); aL1 += __int_as_float(d.w) * lo; aH1 += __int_as_float(d.w) * hi;
    }
    size_t o = (((size_t)n) << 11) + col0;
    f4 tL = aL0 + aL1, tH = aH0 + aH1;
    if (Pown) {
        uint4 pu = *reinterpret_cast<const uint4*>(Pown + o);
        f4 pL, pH;
        up8(pu, pL, pH);
        tL = 2.f * tL - pL;
        tH = 2.f * tH - pH;
    }
    uint4 st;
    st.x = bfpk(tL.x, tL.y); st.y = bfpk(tL.z, tL.w);
    st.z = bfpk(tH.x, tH.y); st.w = bfpk(tH.z, tH.w);
    *reinterpret_cast<uint4*>(Tout + o) = st;
}

// ---------------------------------------------------------------------------
// Chebyshev finalizer. Gather T3 = 2*(L@T2g) - T1 in fp32 regs; stage 4 bf16
// planes {H,T1,T2,T3} in LDS; epilogue GEMM via MFMA (COUT=32) or VALU (=4).
// MFMA: per wave M=16 batches, N=32 co (2 halves), K=128 (K-step kk = plane).
// A/B use identical ci-pair packing -> k-order errors cancel; C/D layout per
// HW-verified mapping col=lane&15, row=(lane>>4)*4+reg.
// ---------------------------------------------------------------------------
template <int COUT, bool OUTBF>
__global__ __launch_bounds__(256, 5) void k_cheb_out(
    const int* __restrict__ rowptr, const int2* __restrict__ cv,
    const ushort_t* __restrict__ T2g,  // gather source (T2), also own-row read
    const ushort_t* __restrict__ T1,   // own-row: Pown + W1 operand
    const ushort_t* __restrict__ H,    // own-row: W0 operand
    const float* __restrict__ W,       // [4*32*COUT] planes {W0,W1,W2,W3}
    const float* __restrict__ bias,    // [COUT]
    void* __restrict__ OUTv)
{
    __shared__ uint_t sPu[4][4][320];                      // [wave][plane][16b x 20]
    __shared__ uint_t sWb[(COUT == 32) ? 2560 : 1];        // bf16 W^T [4][32co][20]
    __shared__ float  sWf[(COUT == 4) ? 512 : 1];          // fp32 W (layer 5)

    int chunk = blockIdx.x & 3;
    int rowblk = blockIdx.x >> 2;
    int wave = threadIdx.x >> 6;
    int lane = threadIdx.x & 63;
    int n = rowblk * 4 + wave;
    int col0 = chunk * 512 + lane * 8;
    int tid = threadIdx.x;

    if constexpr (COUT == 32) {
        // pack W^T to bf16: sWb[p*640 + co*20 + u] = (W[p][2u][co], W[p][2u+1][co])
        for (int idx = tid; idx < 2048; idx += 256) {
            int p = idx >> 9, rem = idx & 511;
            int co = rem >> 4, u = rem & 15;
            sWb[p * 640 + co * 20 + u] =
                bfpk(W[p * 1024 + (2 * u) * 32 + co], W[p * 1024 + (2 * u + 1) * 32 + co]);
        }
    } else {
        for (int idx = tid; idx < 4 * 32 * COUT; idx += 256) sWf[idx] = W[idx];
    }

    int start = rowptr[n], end = rowptr[n + 1];
    f4 aL0 = {0,0,0,0}, aH0 = {0,0,0,0}, aL1 = {0,0,0,0}, aH1 = {0,0,0,0};
    for (int e = start; e < end; e += 8) {
        const int4* q = reinterpret_cast<const int4*>(cv + e);
        int4 a = q[0], b = q[1], c = q[2], d = q[3];
        uint4 u0 = *reinterpret_cast<const uint4*>(T2g + (((size_t)a.x) << 11) + col0);
        uint4 u1 = *reinterpret_cast<const uint4*>(T2g + (((size_t)a.z) << 11) + col0);
        uint4 u2 = *reinterpret_cast<const uint4*>(T2g + (((size_t)b.x) << 11) + col0);
        uint4 u3 = *reinterpret_cast<const uint4*>(T2g + (((size_t)b.z) << 11) + col0);
        uint4 u4 = *reinterpret_cast<const uint4*>(T2g + (((size_t)c.x) << 11) + col0);
        uint4 u5 = *reinterpret_cast<const uint4*>(T2g + (((size_t)c.z) << 11) + col0);
        uint4 u6 = *reinterpret_cast<const uint4*>(T2g + (((size_t)d.x) << 11) + col0);
        uint4 u7 = *reinterpret_cast<const uint4*>(T2g + (((size_t)d.z) << 11) + col0);
        f4 lo, hi;
        up8(u0, lo, hi); aL0 += __int_as_float(a.y) * lo; aH0 += __int_as_float(a.y) * hi;
        up8(u1, lo, hi); aL1 += __int_as_float(a.w) * lo; aH1 += __int_as_float(a.w) * hi;
        up8(u2, lo, hi); aL0 += __int_as_float(b.y) * lo; aH0 += __int_as_float(b.y) * hi;
        up8(u3, lo, hi); aL1 += __int_as_float(b.w) * lo; aH1 += __int_as_float(b.w) * hi;
        up8(u4, lo, hi); aL0 += __int_as_float(c.y) * lo; aH0 += __int_as_float(c.y) * hi;
        up8(u5, lo, hi); aL1 += __int_as_float(c.w) * lo; aH1 += __int_as_float(c.w) * hi;
        up8(u6, lo, hi); aL0 += __int_as_float(d.y) * lo; aH0 += __int_as_float(d.y) * hi;
        up8(u7, lo, hi); aL1 += __int_as_float(d.w) * lo; aH1 += __int_as_float(d.w) * hi;
    }
    size_t o = (((size_t)n) << 11) + col0;

    int g = lane >> 2, qd = lane & 3;        // batch-in-chunk, uint-quad
    int si = g * 20 + qd * 4;
    {   // T3 = 2*U - T1own ; store T3 (plane 3) and T1 (plane 1) packed
        uint4 pu = *reinterpret_cast<const uint4*>(T1 + o);
        f4 pL, pH;
        up8(pu, pL, pH);
        f4 tL = 2.f * (aL0 + aL1) - pL;
        f4 tH = 2.f * (aH0 + aH1) - pH;
        uint4 st;
        st.x = bfpk(tL.x, tL.y); st.y = bfpk(tL.z, tL.w);
        st.z = bfpk(tH.x, tH.y); st.w = bfpk(tH.z, tH.w);
        *reinterpret_cast<uint4*>(&sPu[wave][3][si]) = st;
        *reinterpret_cast<uint4*>(&sPu[wave][1][si]) = pu;
    }
    *reinterpret_cast<uint4*>(&sPu[wave][2][si]) =
        *reinterpret_cast<const uint4*>(T2g + o);
    *reinterpret_cast<uint4*>(&sPu[wave][0][si]) =
        *reinterpret_cast<const uint4*>(H + o);
    __syncthreads();

    if constexpr (COUT == 32) {
        int mr = lane & 15;          // A row (batch) / D col... per fragment rules
        int qk = lane >> 4;          // k-group
        f4 accA = {0,0,0,0}, accB = {0,0,0,0};
#pragma unroll
        for (int kk = 0; kk < 4; ++kk) {   // K-step = plane kk
            bf16x8 af = *reinterpret_cast<const bf16x8*>(&sPu[wave][kk][mr * 20 + qk * 4]);
            bf16x8 b0 = *reinterpret_cast<const bf16x8*>(&sWb[kk * 640 + mr * 20 + qk * 4]);
            bf16x8 b1 = *reinterpret_cast<const bf16x8*>(&sWb[kk * 640 + (16 + mr) * 20 + qk * 4]);
            accA = __builtin_amdgcn_mfma_f32_16x16x32_bf16(af, b0, accA, 0, 0, 0);
            accB = __builtin_amdgcn_mfma_f32_16x16x32_bf16(af, b1, accB, 0, 0, 0);
        }
        // D: col(co) = lane&15 (+16 for accB), row(batch) = (lane>>4)*4 + reg
        int co = lane & 15;
        float bA = bias[co], bB = bias[co + 16];
        ushort_t* OB = (ushort_t*)OUTv;
        size_t obase = (((size_t)n) << 11) + chunk * 512;
#pragma unroll
        for (int r = 0; r < 4; ++r) {
            int gb = (lane >> 4) * 4 + r;
            float vA = accA[r] + bA;
            float vB = accB[r] + bB;
            vA = vA > 0.f ? vA : 0.f;
            vB = vB > 0.f ? vB : 0.f;
            OB[obase + gb * 32 + co]      = bf1(vA);
            OB[obase + gb * 32 + co + 16] = bf1(vB);
        }
    } else {  // COUT == 4 (layer 5): VALU epilogue, fp32 out [N][256]
        int co = lane & 3;
        float o0 = 0.f;
#pragma unroll
        for (int u = 0; u < 16; ++u) {
#pragma unroll
            for (int p = 0; p < 4; ++p) {
                uint_t au = sPu[wave][p][g * 20 + u];
                float alo = __uint_as_float(au << 16);
                float ahi = __uint_as_float(au & 0xffff0000u);
                o0 += alo * sWf[p * 128 + (2 * u) * 4 + co]
                    + ahi * sWf[p * 128 + (2 * u + 1) * 4 + co];
            }
        }
        float r = o0 + bias[co];
        r = r > 0.f ? r : 0.f;
        ((float*)OUTv)[n * 256 + chunk * 64 + lane] = r;
    }
}

// ---------------------------------------------------------------------------
// FC1: split-K over 128 blocks, atomic accumulate. h[b, n*4+c] = H5[n, b*4+c]
// ---------------------------------------------------------------------------
__global__ __launch_bounds__(256) void k_fc1(const float* __restrict__ H5,
                                             const float* __restrict__ fw1,
                                             float* __restrict__ fc1out) {
    __shared__ float hT[128 * 65];
    __shared__ float wS[32 * 128];
    int tid = threadIdx.x;
    int n0 = blockIdx.x * 32;
    for (int idx = tid; idx < 8192; idx += 256) {
        int n_l = idx >> 8;
        int rem = idx & 255;
        int b = rem >> 2, c = rem & 3;
        int kk = n_l * 4 + c;
        hT[kk * 65 + b] = H5[(size_t)(n0 + n_l) * 256 + rem];
    }
    float acc[8][4];
#pragma unroll
    for (int i = 0; i < 8; ++i)
#pragma unroll
        for (int j = 0; j < 4; ++j) acc[i][j] = 0.f;
    int bq = tid >> 5;
    int jq = tid & 31;
    for (int kb = 0; kb < 128; kb += 32) {
        __syncthreads();
        for (int idx = tid; idx < 4096; idx += 256) {
            int kl = idx >> 7, j = idx & 127;
            wS[idx] = fw1[(size_t)(n0 * 4 + kb + kl) * 128 + j];
        }
        __syncthreads();
        for (int kl = 0; kl < 32; ++kl) {
            int kk = kb + kl;
            float4 w = *reinterpret_cast<const float4*>(&wS[kl * 128 + jq * 4]);
#pragma unroll
            for (int bi = 0; bi < 8; ++bi) {
                float h = hT[kk * 65 + bq * 8 + bi];
                acc[bi][0] += h * w.x;
                acc[bi][1] += h * w.y;
                acc[bi][2] += h * w.z;
                acc[bi][3] += h * w.w;
            }
        }
    }
#pragma unroll
    for (int bi = 0; bi < 8; ++bi)
#pragma unroll
        for (int ji = 0; ji < 4; ++ji)
            atomicAdd(&fc1out[(bq * 8 + bi) * 128 + jq * 4 + ji], acc[bi][ji]);
}

__global__ __launch_bounds__(128) void k_fc23(const float* __restrict__ fc1out,
                                              const float* __restrict__ fb1,
                                              const float* __restrict__ fw2,
                                              const float* __restrict__ fb2,
                                              const float* __restrict__ fw3,
                                              const float* __restrict__ fb3,
                                              float* __restrict__ out) {
    int b = blockIdx.x;
    int j = threadIdx.x;
    __shared__ float r[128];
    __shared__ float s1[128];
    r[j] = fc1out[b * 128 + j] + fb1[j];
    __syncthreads();
    float acc = fb2[j];
    for (int i = 0; i < 128; ++i) acc += r[i] * fw2[i * 128 + j];
    s1[j] = acc;
    __syncthreads();
    if (j < 9) {
        float a2 = fb3[j];
        for (int i = 0; i < 128; ++i) a2 += s1[i] * fw3[i * 9 + j];
        out[b * 9 + j] = a2;
    }
}

// ---------------------------------------------------------------------------
extern "C" void kernel_launch(void* const* d_in, const int* in_sizes, int n_in,
                              void* d_out, int out_size, void* d_ws, size_t ws_size,
                              hipStream_t stream) {
    const float* x   = (const float*)d_in[0];
    const int*   src = (const int*)d_in[1];
    const int*   dst = (const int*)d_in[2];
    const float* ew  = (const float*)d_in[3];
    const float* w1  = (const float*)d_in[4];
    const float* b1  = (const float*)d_in[5];
    const float* w2  = (const float*)d_in[6];
    const float* b2  = (const float*)d_in[7];
    const float* w3  = (const float*)d_in[8];
    const float* b3  = (const float*)d_in[9];
    const float* w4  = (const float*)d_in[10];
    const float* b4  = (const float*)d_in[11];
    const float* w5  = (const float*)d_in[12];
    const float* b5  = (const float*)d_in[13];
    const float* fw1 = (const float*)d_in[14];
    const float* fb1 = (const float*)d_in[15];
    const float* fw2 = (const float*)d_in[16];
    const float* fb2 = (const float*)d_in[17];
    const float* fw3 = (const float*)d_in[18];
    const float* fb3 = (const float*)d_in[19];
    float* out = (float*)d_out;

    char* p = (char*)d_ws;
    const size_t XBYTES = (size_t)NN * 2048 * 2;  // 16 MB (bf16)
    ushort_t* X0 = (ushort_t*)(p + 0 * XBYTES);
    ushort_t* X1 = (ushort_t*)(p + 1 * XBYTES);
    ushort_t* X2 = (ushort_t*)(p + 2 * XBYTES);
    ushort_t* X3 = (ushort_t*)(p + 3 * XBYTES);
    size_t off = 4 * XBYTES;
    float* H5     = (float*)(p + off); off += (size_t)NN * 256 * 4;  // fp32
    float* deg    = (float*)(p + off); off += (size_t)NN * 4;
    int*   cnt    = (int*)(p + off);   off += (size_t)NN * 4;
    int*   cursor = (int*)(p + off);   off += (size_t)NN * 4;
    int*   rowptr = (int*)(p + off);   off += (size_t)(NN + 4) * 4;
    int2*  cv     = (int2*)(p + off);  off += (size_t)EPAD * 8;
    float* fc1o   = (float*)(p + off); off += (size_t)BB * 128 * 4;
    float* xn0    = (float*)(p + off); off += (size_t)NN * 64 * 4;
    float* tn1    = (float*)(p + off); off += (size_t)NN * 64 * 4;
    float* tn2    = (float*)(p + off); off += (size_t)NN * 64 * 4;
    float* tn3    = (float*)(p + off); off += (size_t)NN * 64 * 4;
    if (off > ws_size) return;

    hipMemsetAsync(deg, 0, NN * 4, stream);
    hipMemsetAsync(cnt, 0, NN * 4, stream);
    hipMemsetAsync(cv, 0, (size_t)EPAD * 8, stream);
    hipMemsetAsync(fc1o, 0, BB * 128 * 4, stream);

    k_deg_hist<<<EE / 256, 256, 0, stream>>>(src, dst, ew, deg, cnt);
    k_scan<<<1, 1024, 0, stream>>>(cnt, rowptr, cursor);
    k_fill<<<EE / 256, 256, 0, stream>>>(src, dst, ew, deg, cursor, cv);
    k_transpose_x<<<NN / 64, 256, 0, stream>>>(x, xn0);

    // ------------------- layer 1 entirely narrow fp32, then one bf16 expand
    k_spmm_narrow<<<NN, 64, 0, stream>>>(rowptr, cv, xn0, nullptr, tn1, 1.f, 0);
    k_spmm_narrow<<<NN, 64, 0, stream>>>(rowptr, cv, tn1, xn0, tn2, 2.f, 1);
    k_spmm_narrow<<<NN, 64, 0, stream>>>(rowptr, cv, tn2, tn1, tn3, 2.f, 1);
    k_expand1<<<NN, 256, 0, stream>>>(xn0, tn1, tn2, tn3, w1, b1, X3);  // H1 -> X3

    const int GRID4 = (NN / 4) * 4;   // 4096 blocks: 4 chunks x 512 cols
    // ------------------- layers 2-4: S1, S2 pure; S3 fused finalizer
    auto run32 = [&](const ushort_t* H, ushort_t* T1, ushort_t* T2, ushort_t* OUT,
                     const float* W, const float* B) {
        k_spmm_pure<<<GRID4, 256, 0, stream>>>(rowptr, cv, H, nullptr, T1);
        k_spmm_pure<<<GRID4, 256, 0, stream>>>(rowptr, cv, T1, H, T2);
        k_cheb_out<32, true><<<GRID4, 256, 0, stream>>>(rowptr, cv, T2, T1, H, W, B, OUT);
    };
    run32(X3, X0, X1, X2, w2, b2);
    run32(X2, X3, X0, X1, w3, b3);
    run32(X1, X2, X3, X0, w4, b4);

    // ------------------- layer 5 (COUT=4): H=X0 -> H5 fp32 [N][256]
    k_spmm_pure<<<GRID4, 256, 0, stream>>>(rowptr, cv, X0, nullptr, X1);
    k_spmm_pure<<<GRID4, 256, 0, stream>>>(rowptr, cv, X1, X0, X2);
    k_cheb_out<4, false><<<GRID4, 256, 0, stream>>>(rowptr, cv, X2, X1, X0, w5, b5, H5);

    // ------------------- FC head
    k_fc1<<<128, 256, 0, stream>>>(H5, fw1, fc1o);
    k_fc23<<<BB, 128, 0, stream>>>(fc1o, fb1, fw2, fb2, fw3, fb3, out);
}

// Round 10
// 639.977 us; speedup vs baseline: 2.2117x; 1.0018x over previous
//
#include <hip/hip_runtime.h>
#include <cstdint>

#define NN 4096
#define EE 131072
#define BB 64
#define EPAD (EE + 8 * NN)   // CSR rows padded to multiples of 8

typedef float f4 __attribute__((ext_vector_type(4)));
typedef short bf16x8 __attribute__((ext_vector_type(8)));
typedef unsigned short ushort_t;
typedef unsigned int uint_t;

// bf16 helpers
__device__ __forceinline__ void up8(uint4 u, f4& lo, f4& hi) {
    lo.x = __uint_as_float(u.x << 16);
    lo.y = __uint_as_float(u.x & 0xffff0000u);
    lo.z = __uint_as_float(u.y << 16);
    lo.w = __uint_as_float(u.y & 0xffff0000u);
    hi.x = __uint_as_float(u.z << 16);
    hi.y = __uint_as_float(u.z & 0xffff0000u);
    hi.z = __uint_as_float(u.w << 16);
    hi.w = __uint_as_float(u.w & 0xffff0000u);
}
__device__ __forceinline__ uint_t bfpk(float a, float b) {
    uint_t xa = __float_as_uint(a); xa = (xa + 0x7fffu + ((xa >> 16) & 1u)) >> 16;
    uint_t xb = __float_as_uint(b); xb = (xb + 0x7fffu + ((xb >> 16) & 1u));
    return (xa & 0xffffu) | (xb & 0xffff0000u);
}
__device__ __forceinline__ ushort_t bf1(float a) {
    uint_t x = __float_as_uint(a);
    return (ushort_t)((x + 0x7fffu + ((x >> 16) & 1u)) >> 16);
}

// ---------------------------------------------------------------------------
// Graph preprocessing
// ---------------------------------------------------------------------------
__global__ void k_deg_hist(const int* __restrict__ src, const int* __restrict__ dst,
                           const float* __restrict__ ew, float* __restrict__ deg,
                           int* __restrict__ cnt) {
    int e = blockIdx.x * blockDim.x + threadIdx.x;
    if (e >= EE) return;
    atomicAdd(&deg[src[e]], ew[e]);
    atomicAdd(&cnt[dst[e]], 1);
}

__global__ __launch_bounds__(1024) void k_scan(const int* __restrict__ cnt,
                                               int* __restrict__ rowptr,
                                               int* __restrict__ cursor) {
    __shared__ int s[1024];
    int tid = threadIdx.x;
    int p0 = (cnt[tid * 4 + 0] + 7) & ~7;
    int p1 = (cnt[tid * 4 + 1] + 7) & ~7;
    int p2 = (cnt[tid * 4 + 2] + 7) & ~7;
    int p3 = (cnt[tid * 4 + 3] + 7) & ~7;
    int sum = p0 + p1 + p2 + p3;
    s[tid] = sum;
    __syncthreads();
    for (int off = 1; off < 1024; off <<= 1) {
        int t = (tid >= off) ? s[tid - off] : 0;
        __syncthreads();
        s[tid] += t;
        __syncthreads();
    }
    int excl = s[tid] - sum;
    rowptr[tid * 4 + 0] = excl; cursor[tid * 4 + 0] = excl; excl += p0;
    rowptr[tid * 4 + 1] = excl; cursor[tid * 4 + 1] = excl; excl += p1;
    rowptr[tid * 4 + 2] = excl; cursor[tid * 4 + 2] = excl; excl += p2;
    rowptr[tid * 4 + 3] = excl; cursor[tid * 4 + 3] = excl; excl += p3;
    if (tid == 1023) rowptr[4096] = excl;
}

__global__ void k_fill(const int* __restrict__ src, const int* __restrict__ dst,
                       const float* __restrict__ ew, const float* __restrict__ deg,
                       int* __restrict__ cursor, int2* __restrict__ cv) {
    int e = blockIdx.x * blockDim.x + threadIdx.x;
    if (e >= EE) return;
    int s = src[e], d = dst[e];
    int pos = atomicAdd(&cursor[d], 1);
    float ds = deg[s], dd = deg[d];
    float is = ds > 0.f ? rsqrtf(fmaxf(ds, 1e-30f)) : 0.f;
    float id = dd > 0.f ? rsqrtf(fmaxf(dd, 1e-30f)) : 0.f;
    float v = -(is * ew[e] * id);
    cv[pos] = make_int2(s, __float_as_int(v));
}

// ---------------------------------------------------------------------------
// Transpose x [B,N] -> X0 [N,B]  (fp32, layer-1 narrow path)
// ---------------------------------------------------------------------------
__global__ __launch_bounds__(256) void k_transpose_x(const float* __restrict__ x,
                                                     float* __restrict__ X0) {
    __shared__ float s[64 * 65];
    int n0 = blockIdx.x * 64;
    for (int idx = threadIdx.x; idx < 4096; idx += 256) {
        int b = idx >> 6, nl = idx & 63;
        s[nl * 65 + b] = x[(size_t)b * NN + n0 + nl];
    }
    __syncthreads();
    for (int idx = threadIdx.x; idx < 4096; idx += 256) {
        int nl = idx >> 6, b = idx & 63;
        X0[(size_t)(n0 + nl) * 64 + b] = s[nl * 65 + b];
    }
}

// ---------------------------------------------------------------------------
// SpMM narrow (width 64, fp32, layer 1), tail-free x8 gather loop
// ---------------------------------------------------------------------------
__global__ __launch_bounds__(64) void k_spmm_narrow(const int* __restrict__ rowptr,
                                                    const int2* __restrict__ cv,
                                                    const float* __restrict__ Zin,
                                                    const float* __restrict__ Tprev,
                                                    float* __restrict__ Tout,
                                                    float alpha, int useprev) {
    int n = blockIdx.x;
    int lane = threadIdx.x;
    int start = rowptr[n], end = rowptr[n + 1];
    float acc = 0.f;
    for (int e = start; e < end; e += 8) {
        const int4* q = reinterpret_cast<const int4*>(cv + e);
        int4 a = q[0], b = q[1], c = q[2], d = q[3];
        float z0 = Zin[((size_t)a.x << 6) + lane];
        float z1 = Zin[((size_t)a.z << 6) + lane];
        float z2 = Zin[((size_t)b.x << 6) + lane];
        float z3 = Zin[((size_t)b.z << 6) + lane];
        float z4 = Zin[((size_t)c.x << 6) + lane];
        float z5 = Zin[((size_t)c.z << 6) + lane];
        float z6 = Zin[((size_t)d.x << 6) + lane];
        float z7 = Zin[((size_t)d.z << 6) + lane];
        acc += __int_as_float(a.y) * z0 + __int_as_float(a.w) * z1
             + __int_as_float(b.y) * z2 + __int_as_float(b.w) * z3
             + __int_as_float(c.y) * z4 + __int_as_float(c.w) * z5
             + __int_as_float(d.y) * z6 + __int_as_float(d.w) * z7;
    }
    size_t o = ((size_t)n << 6) + lane;
    float r = alpha * acc;
    if (useprev) r -= Tprev[o];
    Tout[o] = r;
}

// ---------------------------------------------------------------------------
// Layer-1 expand -> bf16 H
// ---------------------------------------------------------------------------
__global__ __launch_bounds__(256) void k_expand1(const float* __restrict__ T0,
                                                 const float* __restrict__ T1,
                                                 const float* __restrict__ T2,
                                                 const float* __restrict__ T3,
                                                 const float* __restrict__ w1,
                                                 const float* __restrict__ b1,
                                                 ushort_t* __restrict__ H) {
    __shared__ float sT[4][64];
    __shared__ float sW[128];
    __shared__ float sB[32];
    int n = blockIdx.x, tid = threadIdx.x;
    {
        int k = tid >> 6, b = tid & 63;
        const float* Tk = (k == 0) ? T0 : (k == 1) ? T1 : (k == 2) ? T2 : T3;
        sT[k][b] = Tk[(size_t)n * 64 + b];
    }
    if (tid < 128) sW[tid] = w1[tid];
    if (tid < 32) sB[tid] = b1[tid];
    __syncthreads();
    int col0 = tid * 8;
    int b = tid >> 2;
    int co0 = col0 & 31;
    float t0 = sT[0][b], t1 = sT[1][b], t2 = sT[2][b], t3 = sT[3][b];
    float r[8];
#pragma unroll
    for (int j = 0; j < 8; ++j) {
        int co = co0 + j;
        float v = t0 * sW[co] + t1 * sW[32 + co] + t2 * sW[64 + co] + t3 * sW[96 + co] + sB[co];
        r[j] = v > 0.f ? v : 0.f;
    }
    uint4 st;
    st.x = bfpk(r[0], r[1]); st.y = bfpk(r[2], r[3]);
    st.z = bfpk(r[4], r[5]); st.w = bfpk(r[6], r[7]);
    *reinterpret_cast<uint4*>(H + (size_t)n * 2048 + col0) = st;
}

// ---------------------------------------------------------------------------
// Pure wide SpMM (bf16, fp32 accumulate), 4 chunks x 512 cols, 16B gathers.
// ---------------------------------------------------------------------------
__global__ __launch_bounds__(256) void k_spmm_pure(const int* __restrict__ rowptr,
                                                   const int2* __restrict__ cv,
                                                   const ushort_t* __restrict__ Zg,
                                                   const ushort_t* __restrict__ Pown,
                                                   ushort_t* __restrict__ Tout) {
    int chunk = blockIdx.x & 3;
    int rowblk = blockIdx.x >> 2;
    int wave = threadIdx.x >> 6;
    int lane = threadIdx.x & 63;
    int n = rowblk * 4 + wave;
    int col0 = chunk * 512 + lane * 8;

    int start = rowptr[n], end = rowptr[n + 1];
    f4 aL0 = {0,0,0,0}, aH0 = {0,0,0,0}, aL1 = {0,0,0,0}, aH1 = {0,0,0,0};
    for (int e = start; e < end; e += 8) {
        const int4* q = reinterpret_cast<const int4*>(cv + e);
        int4 a = q[0], b = q[1], c = q[2], d = q[3];
        uint4 u0 = *reinterpret_cast<const uint4*>(Zg + (((size_t)a.x) << 11) + col0);
        uint4 u1 = *reinterpret_cast<const uint4*>(Zg + (((size_t)a.z) << 11) + col0);
        uint4 u2 = *reinterpret_cast<const uint4*>(Zg + (((size_t)b.x) << 11) + col0);
        uint4 u3 = *reinterpret_cast<const uint4*>(Zg + (((size_t)b.z) << 11) + col0);
        uint4 u4 = *reinterpret_cast<const uint4*>(Zg + (((size_t)c.x) << 11) + col0);
        uint4 u5 = *reinterpret_cast<const uint4*>(Zg + (((size_t)c.z) << 11) + col0);
        uint4 u6 = *reinterpret_cast<const uint4*>(Zg + (((size_t)d.x) << 11) + col0);
        uint4 u7 = *reinterpret_cast<const uint4*>(Zg + (((size_t)d.z) << 11) + col0);
        f4 lo, hi;
        up8(u0, lo, hi); aL0 += __int_as_float(a.y) * lo; aH0 += __int_as_float(a.y) * hi;
        up8(u1, lo, hi); aL1 += __int_as_float(a.w) * lo; aH1 += __int_as_float(a.w) * hi;
        up8(u2, lo, hi); aL0 += __int_as_float(b.y) * lo; aH0 += __int_as_float(b.y) * hi;
        up8(u3, lo, hi); aL1 += __int_as_float(b.w) * lo; aH1 += __int_as_float(b.w) * hi;
        up8(u4, lo, hi); aL0 += __int_as_float(c.y) * lo; aH0 += __int_as_float(c.y) * hi;
        up8(u5, lo, hi); aL1 += __int_as_float(c.w) * lo; aH1 += __int_as_float(c.w) * hi;
        up8(u6, lo, hi); aL0 += __int_as_float(d.y) * lo; aH0 += __int_as_float(d.y) * hi;
        up8(u7, lo, hi); aL1 += __int_as_float(d.w) * lo; aH1 += __int_as_float(d.w) * hi;
    }
    size_t o = (((size_t)n) << 11) + col0;
    f4 tL = aL0 + aL1, tH = aH0 + aH1;
    if (Pown) {
        uint4 pu = *reinterpret_cast<const uint4*>(Pown + o);
        f4 pL, pH;
        up8(pu, pL, pH);
        tL = 2.f * tL - pL;
        tH = 2.f * tH - pH;
    }
    uint4 st;
    st.x = bfpk(tL.x, tL.y); st.y = bfpk(tL.z, tL.w);
    st.z = bfpk(tH.x, tH.y); st.w = bfpk(tH.z, tH.w);
    *reinterpret_cast<uint4*>(Tout + o) = st;
}

// ---------------------------------------------------------------------------
// Chebyshev finalizer. Gather T3 = 2*(L@T2g) - T1 in fp32 regs; stage 4 bf16
// planes {H,T1,T2,T3} in LDS; epilogue GEMM via MFMA (COUT=32) or VALU (=4).
// MFMA: per wave M=16 batches, N=32 co (2 halves), K=128 (K-step kk = plane).
// A/B use identical ci-pair packing -> k-order errors cancel; C/D layout per
// HW-verified mapping col=lane&15, row=(lane>>4)*4+reg.
// ---------------------------------------------------------------------------
template <int COUT, bool OUTBF>
__global__ __launch_bounds__(256, 5) void k_cheb_out(
    const int* __restrict__ rowptr, const int2* __restrict__ cv,
    const ushort_t* __restrict__ T2g,  // gather source (T2), also own-row read
    const ushort_t* __restrict__ T1,   // own-row: Pown + W1 operand
    const ushort_t* __restrict__ H,    // own-row: W0 operand
    const float* __restrict__ W,       // [4*32*COUT] planes {W0,W1,W2,W3}
    const float* __restrict__ bias,    // [COUT]
    void* __restrict__ OUTv)
{
    __shared__ uint_t sPu[4][4][320];                      // [wave][plane][16b x 20]
    __shared__ uint_t sWb[(COUT == 32) ? 2560 : 1];        // bf16 W^T [4][32co][20]
    __shared__ float  sWf[(COUT == 4) ? 512 : 1];          // fp32 W (layer 5)

    int chunk = blockIdx.x & 3;
    int rowblk = blockIdx.x >> 2;
    int wave = threadIdx.x >> 6;
    int lane = threadIdx.x & 63;
    int n = rowblk * 4 + wave;
    int col0 = chunk * 512 + lane * 8;
    int tid = threadIdx.x;

    if constexpr (COUT == 32) {
        // pack W^T to bf16: sWb[p*640 + co*20 + u] = (W[p][2u][co], W[p][2u+1][co])
        for (int idx = tid; idx < 2048; idx += 256) {
            int p = idx >> 9, rem = idx & 511;
            int co = rem >> 4, u = rem & 15;
            sWb[p * 640 + co * 20 + u] =
                bfpk(W[p * 1024 + (2 * u) * 32 + co], W[p * 1024 + (2 * u + 1) * 32 + co]);
        }
    } else {
        for (int idx = tid; idx < 4 * 32 * COUT; idx += 256) sWf[idx] = W[idx];
    }

    int start = rowptr[n], end = rowptr[n + 1];
    f4 aL0 = {0,0,0,0}, aH0 = {0,0,0,0}, aL1 = {0,0,0,0}, aH1 = {0,0,0,0};
    for (int e = start; e < end; e += 8) {
        const int4* q = reinterpret_cast<const int4*>(cv + e);
        int4 a = q[0], b = q[1], c = q[2], d = q[3];
        uint4 u0 = *reinterpret_cast<const uint4*>(T2g + (((size_t)a.x) << 11) + col0);
        uint4 u1 = *reinterpret_cast<const uint4*>(T2g + (((size_t)a.z) << 11) + col0);
        uint4 u2 = *reinterpret_cast<const uint4*>(T2g + (((size_t)b.x) << 11) + col0);
        uint4 u3 = *reinterpret_cast<const uint4*>(T2g + (((size_t)b.z) << 11) + col0);
        uint4 u4 = *reinterpret_cast<const uint4*>(T2g + (((size_t)c.x) << 11) + col0);
        uint4 u5 = *reinterpret_cast<const uint4*>(T2g + (((size_t)c.z) << 11) + col0);
        uint4 u6 = *reinterpret_cast<const uint4*>(T2g + (((size_t)d.x) << 11) + col0);
        uint4 u7 = *reinterpret_cast<const uint4*>(T2g + (((size_t)d.z) << 11) + col0);
        f4 lo, hi;
        up8(u0, lo, hi); aL0 += __int_as_float(a.y) * lo; aH0 += __int_as_float(a.y) * hi;
        up8(u1, lo, hi); aL1 += __int_as_float(a.w) * lo; aH1 += __int_as_float(a.w) * hi;
        up8(u2, lo, hi); aL0 += __int_as_float(b.y) * lo; aH0 += __int_as_float(b.y) * hi;
        up8(u3, lo, hi); aL1 += __int_as_float(b.w) * lo; aH1 += __int_as_float(b.w) * hi;
        up8(u4, lo, hi); aL0 += __int_as_float(c.y) * lo; aH0 += __int_as_float(c.y) * hi;
        up8(u5, lo, hi); aL1 += __int_as_float(c.w) * lo; aH1 += __int_as_float(c.w) * hi;
        up8(u6, lo, hi); aL0 += __int_as_float(d.y) * lo; aH0 += __int_as_float(d.y) * hi;
        up8(u7, lo, hi); aL1 += __int_as_float(d.w) * lo; aH1 += __int_as_float(d.w) * hi;
    }
    size_t o = (((size_t)n) << 11) + col0;

    int g = lane >> 2, qd = lane & 3;        // batch-in-chunk, uint-quad
    int si = g * 20 + qd * 4;
    {   // T3 = 2*U - T1own ; store T3 (plane 3) and T1 (plane 1) packed
        uint4 pu = *reinterpret_cast<const uint4*>(T1 + o);
        f4 pL, pH;
        up8(pu, pL, pH);
        f4 tL = 2.f * (aL0 + aL1) - pL;
        f4 tH = 2.f * (aH0 + aH1) - pH;
        uint4 st;
        st.x = bfpk(tL.x, tL.y); st.y = bfpk(tL.z, tL.w);
        st.z = bfpk(tH.x, tH.y); st.w = bfpk(tH.z, tH.w);
        *reinterpret_cast<uint4*>(&sPu[wave][3][si]) = st;
        *reinterpret_cast<uint4*>(&sPu[wave][1][si]) = pu;
    }
    *reinterpret_cast<uint4*>(&sPu[wave][2][si]) =
        *reinterpret_cast<const uint4*>(T2g + o);
    *reinterpret_cast<uint4*>(&sPu[wave][0][si]) =
        *reinterpret_cast<const uint4*>(H + o);
    __syncthreads();

    if constexpr (COUT == 32) {
        int mr = lane & 15;          // A row (batch) / D col... per fragment rules
        int qk = lane >> 4;          // k-group
        f4 accA = {0,0,0,0}, accB = {0,0,0,0};
#pragma unroll
        for (int kk = 0; kk < 4; ++kk) {   // K-step = plane kk
            bf16x8 af = *reinterpret_cast<const bf16x8*>(&sPu[wave][kk][mr * 20 + qk * 4]);
            bf16x8 b0 = *reinterpret_cast<const bf16x8*>(&sWb[kk * 640 + mr * 20 + qk * 4]);
            bf16x8 b1 = *reinterpret_cast<const bf16x8*>(&sWb[kk * 640 + (16 + mr) * 20 + qk * 4]);
            accA = __builtin_amdgcn_mfma_f32_16x16x32_bf16(af, b0, accA, 0, 0, 0);
            accB = __builtin_amdgcn_mfma_f32_16x16x32_bf16(af, b1, accB, 0, 0, 0);
        }
        // D: col(co) = lane&15 (+16 for accB), row(batch) = (lane>>4)*4 + reg
        int co = lane & 15;
        float bA = bias[co], bB = bias[co + 16];
        ushort_t* OB = (ushort_t*)OUTv;
        size_t obase = (((size_t)n) << 11) + chunk * 512;
#pragma unroll
        for (int r = 0; r < 4; ++r) {
            int gb = (lane >> 4) * 4 + r;
            float vA = accA[r] + bA;
            float vB = accB[r] + bB;
            vA = vA > 0.f ? vA : 0.f;
            vB = vB > 0.f ? vB : 0.f;
            OB[obase + gb * 32 + co]      = bf1(vA);
            OB[obase + gb * 32 + co + 16] = bf1(vB);
        }
    } else {  // COUT == 4 (layer 5): VALU epilogue, fp32 out [N][256]
        int co = lane & 3;
        float o0 = 0.f;
#pragma unroll
        for (int u = 0; u < 16; ++u) {
#pragma unroll
            for (int p = 0; p < 4; ++p) {
                uint_t au = sPu[wave][p][g * 20 + u];
                float alo = __uint_as_float(au << 16);
                float ahi = __uint_as_float(au & 0xffff0000u);
                o0 += alo * sWf[p * 128 + (2 * u) * 4 + co]
                    + ahi * sWf[p * 128 + (2 * u + 1) * 4 + co];
            }
        }
        float r = o0 + bias[co];
        r = r > 0.f ? r : 0.f;
        ((float*)OUTv)[n * 256 + chunk * 64 + lane] = r;
    }
}

// ---------------------------------------------------------------------------
// FC1: split-K over 128 blocks, atomic accumulate. h[b, n*4+c] = H5[n, b*4+c]
// ---------------------------------------------------------------------------
__global__ __launch_bounds__(256) void k_fc1(const float* __restrict__ H5,
                                             const float* __restrict__ fw1,
                                             float* __restrict__ fc1out) {
    __shared__ float hT[128 * 65];
    __shared__ float wS[32 * 128];
    int tid = threadIdx.x;
    int n0 = blockIdx.x * 32;
    for (int idx = tid; idx < 8192; idx += 256) {
        int n_l = idx >> 8;
        int rem = idx & 255;
        int b = rem >> 2, c = rem & 3;
        int kk = n_l * 4 + c;
        hT[kk * 65 + b] = H5[(size_t)(n0 + n_l) * 256 + rem];
    }
    float acc[8][4];
#pragma unroll
    for (int i = 0; i < 8; ++i)
#pragma unroll
        for (int j = 0; j < 4; ++j) acc[i][j] = 0.f;
    int bq = tid >> 5;
    int jq = tid & 31;
    for (int kb = 0; kb < 128; kb += 32) {
        __syncthreads();
        for (int idx = tid; idx < 4096; idx += 256) {
            int kl = idx >> 7, j = idx & 127;
            wS[idx] = fw1[(size_t)(n0 * 4 + kb + kl) * 128 + j];
        }
        __syncthreads();
        for (int kl = 0; kl < 32; ++kl) {
            int kk = kb + kl;
            float4 w = *reinterpret_cast<const float4*>(&wS[kl * 128 + jq * 4]);
#pragma unroll
            for (int bi = 0; bi < 8; ++bi) {
                float h = hT[kk * 65 + bq * 8 + bi];
                acc[bi][0] += h * w.x;
                acc[bi][1] += h * w.y;
                acc[bi][2] += h * w.z;
                acc[bi][3] += h * w.w;
            }
        }
    }
#pragma unroll
    for (int bi = 0; bi < 8; ++bi)
#pragma unroll
        for (int ji = 0; ji < 4; ++ji)
            atomicAdd(&fc1out[(bq * 8 + bi) * 128 + jq * 4 + ji], acc[bi][ji]);
}

__global__ __launch_bounds__(128) void k_fc23(const float* __restrict__ fc1out,
                                              const float* __restrict__ fb1,
                                              const float* __restrict__ fw2,
                                              const float* __restrict__ fb2,
                                              const float* __restrict__ fw3,
                                              const float* __restrict__ fb3,
                                              float* __restrict__ out) {
    int b = blockIdx.x;
    int j = threadIdx.x;
    __shared__ float r[128];
    __shared__ float s1[128];
    r[j] = fc1out[b * 128 + j] + fb1[j];
    __syncthreads();
    float acc = fb2[j];
    for (int i = 0; i < 128; ++i) acc += r[i] * fw2[i * 128 + j];
    s1[j] = acc;
    __syncthreads();
    if (j < 9) {
        float a2 = fb3[j];
        for (int i = 0; i < 128; ++i) a2 += s1[i] * fw3[i * 9 + j];
        out[b * 9 + j] = a2;
    }
}

// ---------------------------------------------------------------------------
extern "C" void kernel_launch(void* const* d_in, const int* in_sizes, int n_in,
                              void* d_out, int out_size, void* d_ws, size_t ws_size,
                              hipStream_t stream) {
    const float* x   = (const float*)d_in[0];
    const int*   src = (const int*)d_in[1];
    const int*   dst = (const int*)d_in[2];
    const float* ew  = (const float*)d_in[3];
    const float* w1  = (const float*)d_in[4];
    const float* b1  = (const float*)d_in[5];
    const float* w2  = (const float*)d_in[6];
    const float* b2  = (const float*)d_in[7];
    const float* w3  = (const float*)d_in[8];
    const float* b3  = (const float*)d_in[9];
    const float* w4  = (const float*)d_in[10];
    const float* b4  = (const float*)d_in[11];
    const float* w5  = (const float*)d_in[12];
    const float* b5  = (const float*)d_in[13];
    const float* fw1 = (const float*)d_in[14];
    const float* fb1 = (const float*)d_in[15];
    const float* fw2 = (const float*)d_in[16];
    const float* fb2 = (const float*)d_in[17];
    const float* fw3 = (const float*)d_in[18];
    const float* fb3 = (const float*)d_in[19];
    float* out = (float*)d_out;

    char* p = (char*)d_ws;
    const size_t XBYTES = (size_t)NN * 2048 * 2;  // 16 MB (bf16)
    ushort_t* X0 = (ushort_t*)(p + 0 * XBYTES);
    ushort_t* X1 = (ushort_t*)(p + 1 * XBYTES);
    ushort_t* X2 = (ushort_t*)(p + 2 * XBYTES);
    ushort_t* X3 = (ushort_t*)(p + 3 * XBYTES);
    size_t off = 4 * XBYTES;
    float* H5     = (float*)(p + off); off += (size_t)NN * 256 * 4;  // fp32
    float* deg    = (float*)(p + off); off += (size_t)NN * 4;
    int*   cnt    = (int*)(p + off);   off += (size_t)NN * 4;
    int*   cursor = (int*)(p + off);   off += (size_t)NN * 4;
    int*   rowptr = (int*)(p + off);   off += (size_t)(NN + 4) * 4;
    int2*  cv     = (int2*)(p + off);  off += (size_t)EPAD * 8;
    float* fc1o   = (float*)(p + off); off += (size_t)BB * 128 * 4;
    float* xn0    = (float*)(p + off); off += (size_t)NN * 64 * 4;
    float* tn1    = (float*)(p + off); off += (size_t)NN * 64 * 4;
    float* tn2    = (float*)(p + off); off += (size_t)NN * 64 * 4;
    float* tn3    = (float*)(p + off); off += (size_t)NN * 64 * 4;
    if (off > ws_size) return;

    hipMemsetAsync(deg, 0, NN * 4, stream);
    hipMemsetAsync(cnt, 0, NN * 4, stream);
    hipMemsetAsync(cv, 0, (size_t)EPAD * 8, stream);
    hipMemsetAsync(fc1o, 0, BB * 128 * 4, stream);

    k_deg_hist<<<EE / 256, 256, 0, stream>>>(src, dst, ew, deg, cnt);
    k_scan<<<1, 1024, 0, stream>>>(cnt, rowptr, cursor);
    k_fill<<<EE / 256, 256, 0, stream>>>(src, dst, ew, deg, cursor, cv);
    k_transpose_x<<<NN / 64, 256, 0, stream>>>(x, xn0);

    // ------------------- layer 1 entirely narrow fp32, then one bf16 expand
    k_spmm_narrow<<<NN, 64, 0, stream>>>(rowptr, cv, xn0, nullptr, tn1, 1.f, 0);
    k_spmm_narrow<<<NN, 64, 0, stream>>>(rowptr, cv, tn1, xn0, tn2, 2.f, 1);
    k_spmm_narrow<<<NN, 64, 0, stream>>>(rowptr, cv, tn2, tn1, tn3, 2.f, 1);
    k_expand1<<<NN, 256, 0, stream>>>(xn0, tn1, tn2, tn3, w1, b1, X3);  // H1 -> X3

    const int GRID4 = (NN / 4) * 4;   // 4096 blocks: 4 chunks x 512 cols
    // ------------------- layers 2-4: S1, S2 pure; S3 fused finalizer
    auto run32 = [&](const ushort_t* H, ushort_t* T1, ushort_t* T2, ushort_t* OUT,
                     const float* W, const float* B) {
        k_spmm_pure<<<GRID4, 256, 0, stream>>>(rowptr, cv, H, nullptr, T1);
        k_spmm_pure<<<GRID4, 256, 0, stream>>>(rowptr, cv, T1, H, T2);
        k_cheb_out<32, true><<<GRID4, 256, 0, stream>>>(rowptr, cv, T2, T1, H, W, B, OUT);
    };
    run32(X3, X0, X1, X2, w2, b2);
    run32(X2, X3, X0, X1, w3, b3);
    run32(X1, X2, X3, X0, w4, b4);

    // ------------------- layer 5 (COUT=4): H=X0 -> H5 fp32 [N][256]
    k_spmm_pure<<<GRID4, 256, 0, stream>>>(rowptr, cv, X0, nullptr, X1);
    k_spmm_pure<<<GRID4, 256, 0, stream>>>(rowptr, cv, X1, X0, X2);
    k_cheb_out<4, false><<<GRID4, 256, 0, stream>>>(rowptr, cv, X2, X1, X0, w5, b5, H5);

    // ------------------- FC head
    k_fc1<<<128, 256, 0, stream>>>(H5, fw1, fc1o);
    k_fc23<<<BB, 128, 0, stream>>>(fc1o, fb1, fw2, fb2, fw3, fb3, out);
}

// Round 11
// 628.883 us; speedup vs baseline: 2.2508x; 1.0176x over previous
//
#include <hip/hip_runtime.h>
#include <cstdint>

#define NN 4096
#define EE 131072
#define BB 64
#define EPAD (EE + 8 * NN)   // CSR rows padded to multiples of 8

typedef float f4 __attribute__((ext_vector_type(4)));
typedef short bf16x8 __attribute__((ext_vector_type(8)));
typedef unsigned short ushort_t;
typedef unsigned int uint_t;

// bf16 helpers
__device__ __forceinline__ void up8(uint4 u, f4& lo, f4& hi) {
    lo.x = __uint_as_float(u.x << 16);
    lo.y = __uint_as_float(u.x & 0xffff0000u);
    lo.z = __uint_as_float(u.y << 16);
    lo.w = __uint_as_float(u.y & 0xffff0000u);
    hi.x = __uint_as_float(u.z << 16);
    hi.y = __uint_as_float(u.z & 0xffff0000u);
    hi.z = __uint_as_float(u.w << 16);
    hi.w = __uint_as_float(u.w & 0xffff0000u);
}
__device__ __forceinline__ uint_t bfpk(float a, float b) {
    uint_t xa = __float_as_uint(a); xa = (xa + 0x7fffu + ((xa >> 16) & 1u)) >> 16;
    uint_t xb = __float_as_uint(b); xb = (xb + 0x7fffu + ((xb >> 16) & 1u));
    return (xa & 0xffffu) | (xb & 0xffff0000u);
}
__device__ __forceinline__ ushort_t bf1(float a) {
    uint_t x = __float_as_uint(a);
    return (ushort_t)((x + 0x7fffu + ((x >> 16) & 1u)) >> 16);
}

// ---------------------------------------------------------------------------
// Graph preprocessing
// ---------------------------------------------------------------------------
__global__ void k_deg_hist(const int* __restrict__ src, const int* __restrict__ dst,
                           const float* __restrict__ ew, float* __restrict__ deg,
                           int* __restrict__ cnt) {
    int e = blockIdx.x * blockDim.x + threadIdx.x;
    if (e >= EE) return;
    atomicAdd(&deg[src[e]], ew[e]);
    atomicAdd(&cnt[dst[e]], 1);
}

__global__ __launch_bounds__(1024) void k_scan(const int* __restrict__ cnt,
                                               int* __restrict__ rowptr,
                                               int* __restrict__ cursor) {
    __shared__ int s[1024];
    int tid = threadIdx.x;
    int p0 = (cnt[tid * 4 + 0] + 7) & ~7;
    int p1 = (cnt[tid * 4 + 1] + 7) & ~7;
    int p2 = (cnt[tid * 4 + 2] + 7) & ~7;
    int p3 = (cnt[tid * 4 + 3] + 7) & ~7;
    int sum = p0 + p1 + p2 + p3;
    s[tid] = sum;
    __syncthreads();
    for (int off = 1; off < 1024; off <<= 1) {
        int t = (tid >= off) ? s[tid - off] : 0;
        __syncthreads();
        s[tid] += t;
        __syncthreads();
    }
    int excl = s[tid] - sum;
    rowptr[tid * 4 + 0] = excl; cursor[tid * 4 + 0] = excl; excl += p0;
    rowptr[tid * 4 + 1] = excl; cursor[tid * 4 + 1] = excl; excl += p1;
    rowptr[tid * 4 + 2] = excl; cursor[tid * 4 + 2] = excl; excl += p2;
    rowptr[tid * 4 + 3] = excl; cursor[tid * 4 + 3] = excl; excl += p3;
    if (tid == 1023) rowptr[4096] = excl;
}

__global__ void k_fill(const int* __restrict__ src, const int* __restrict__ dst,
                       const float* __restrict__ ew, const float* __restrict__ deg,
                       int* __restrict__ cursor, int2* __restrict__ cv) {
    int e = blockIdx.x * blockDim.x + threadIdx.x;
    if (e >= EE) return;
    int s = src[e], d = dst[e];
    int pos = atomicAdd(&cursor[d], 1);
    float ds = deg[s], dd = deg[d];
    float is = ds > 0.f ? rsqrtf(fmaxf(ds, 1e-30f)) : 0.f;
    float id = dd > 0.f ? rsqrtf(fmaxf(dd, 1e-30f)) : 0.f;
    float v = -(is * ew[e] * id);
    cv[pos] = make_int2(s, __float_as_int(v));
}

// ---------------------------------------------------------------------------
// One-time weight pre-pack into MFMA B-fragment order (bf16 pairs):
// Wb[L][kk*512 + co*16 + u] = (W_L[kk][2u][co], W_L[kk][2u+1][co])
// L = 0..2 -> w2,w3,w4 ([4][32][32]); L = 3 -> w5 ([4][32][4], co>=4 zero).
// ---------------------------------------------------------------------------
__global__ __launch_bounds__(256) void k_packw(const float* __restrict__ w2,
                                               const float* __restrict__ w3,
                                               const float* __restrict__ w4,
                                               const float* __restrict__ w5,
                                               uint_t* __restrict__ Wb) {
    int idx = blockIdx.x * 256 + threadIdx.x;  // 0..8191
    int L = idx >> 11, rem = idx & 2047;
    int kk = rem >> 9, r2 = rem & 511, co = r2 >> 4, u = r2 & 15;
    float lo, hi;
    if (L < 3) {
        const float* W = (L == 0) ? w2 : (L == 1) ? w3 : w4;
        lo = W[kk * 1024 + (2 * u) * 32 + co];
        hi = W[kk * 1024 + (2 * u + 1) * 32 + co];
    } else {
        lo = (co < 4) ? w5[kk * 128 + (2 * u) * 4 + co] : 0.f;
        hi = (co < 4) ? w5[kk * 128 + (2 * u + 1) * 4 + co] : 0.f;
    }
    Wb[idx] = bfpk(lo, hi);
}

// ---------------------------------------------------------------------------
// Transpose x [B,N] -> X0 [N,B]  (fp32, layer-1 narrow path)
// ---------------------------------------------------------------------------
__global__ __launch_bounds__(256) void k_transpose_x(const float* __restrict__ x,
                                                     float* __restrict__ X0) {
    __shared__ float s[64 * 65];
    int n0 = blockIdx.x * 64;
    for (int idx = threadIdx.x; idx < 4096; idx += 256) {
        int b = idx >> 6, nl = idx & 63;
        s[nl * 65 + b] = x[(size_t)b * NN + n0 + nl];
    }
    __syncthreads();
    for (int idx = threadIdx.x; idx < 4096; idx += 256) {
        int nl = idx >> 6, b = idx & 63;
        X0[(size_t)(n0 + nl) * 64 + b] = s[nl * 65 + b];
    }
}

// ---------------------------------------------------------------------------
// SpMM narrow (width 64, fp32, layer 1), tail-free x8 gather loop
// ---------------------------------------------------------------------------
__global__ __launch_bounds__(64) void k_spmm_narrow(const int* __restrict__ rowptr,
                                                    const int2* __restrict__ cv,
                                                    const float* __restrict__ Zin,
                                                    const float* __restrict__ Tprev,
                                                    float* __restrict__ Tout,
                                                    float alpha, int useprev) {
    int n = blockIdx.x;
    int lane = threadIdx.x;
    int start = rowptr[n], end = rowptr[n + 1];
    float acc = 0.f;
    for (int e = start; e < end; e += 8) {
        const int4* q = reinterpret_cast<const int4*>(cv + e);
        int4 a = q[0], b = q[1], c = q[2], d = q[3];
        float z0 = Zin[((size_t)a.x << 6) + lane];
        float z1 = Zin[((size_t)a.z << 6) + lane];
        float z2 = Zin[((size_t)b.x << 6) + lane];
        float z3 = Zin[((size_t)b.z << 6) + lane];
        float z4 = Zin[((size_t)c.x << 6) + lane];
        float z5 = Zin[((size_t)c.z << 6) + lane];
        float z6 = Zin[((size_t)d.x << 6) + lane];
        float z7 = Zin[((size_t)d.z << 6) + lane];
        acc += __int_as_float(a.y) * z0 + __int_as_float(a.w) * z1
             + __int_as_float(b.y) * z2 + __int_as_float(b.w) * z3
             + __int_as_float(c.y) * z4 + __int_as_float(c.w) * z5
             + __int_as_float(d.y) * z6 + __int_as_float(d.w) * z7;
    }
    size_t o = ((size_t)n << 6) + lane;
    float r = alpha * acc;
    if (useprev) r -= Tprev[o];
    Tout[o] = r;
}

// ---------------------------------------------------------------------------
// Layer-1 expand -> bf16 H
// ---------------------------------------------------------------------------
__global__ __launch_bounds__(256) void k_expand1(const float* __restrict__ T0,
                                                 const float* __restrict__ T1,
                                                 const float* __restrict__ T2,
                                                 const float* __restrict__ T3,
                                                 const float* __restrict__ w1,
                                                 const float* __restrict__ b1,
                                                 ushort_t* __restrict__ H) {
    __shared__ float sT[4][64];
    __shared__ float sW[128];
    __shared__ float sB[32];
    int n = blockIdx.x, tid = threadIdx.x;
    {
        int k = tid >> 6, b = tid & 63;
        const float* Tk = (k == 0) ? T0 : (k == 1) ? T1 : (k == 2) ? T2 : T3;
        sT[k][b] = Tk[(size_t)n * 64 + b];
    }
    if (tid < 128) sW[tid] = w1[tid];
    if (tid < 32) sB[tid] = b1[tid];
    __syncthreads();
    int col0 = tid * 8;
    int b = tid >> 2;
    int co0 = col0 & 31;
    float t0 = sT[0][b], t1 = sT[1][b], t2 = sT[2][b], t3 = sT[3][b];
    float r[8];
#pragma unroll
    for (int j = 0; j < 8; ++j) {
        int co = co0 + j;
        float v = t0 * sW[co] + t1 * sW[32 + co] + t2 * sW[64 + co] + t3 * sW[96 + co] + sB[co];
        r[j] = v > 0.f ? v : 0.f;
    }
    uint4 st;
    st.x = bfpk(r[0], r[1]); st.y = bfpk(r[2], r[3]);
    st.z = bfpk(r[4], r[5]); st.w = bfpk(r[6], r[7]);
    *reinterpret_cast<uint4*>(H + (size_t)n * 2048 + col0) = st;
}

// ---------------------------------------------------------------------------
// Pure wide SpMM (bf16, fp32 accumulate), 4 chunks x 512 cols, 16B gathers.
// ---------------------------------------------------------------------------
__global__ __launch_bounds__(256) void k_spmm_pure(const int* __restrict__ rowptr,
                                                   const int2* __restrict__ cv,
                                                   const ushort_t* __restrict__ Zg,
                                                   const ushort_t* __restrict__ Pown,
                                                   ushort_t* __restrict__ Tout) {
    int chunk = blockIdx.x & 3;
    int rowblk = blockIdx.x >> 2;
    int wave = threadIdx.x >> 6;
    int lane = threadIdx.x & 63;
    int n = rowblk * 4 + wave;
    int col0 = chunk * 512 + lane * 8;

    int start = rowptr[n], end = rowptr[n + 1];
    f4 aL0 = {0,0,0,0}, aH0 = {0,0,0,0}, aL1 = {0,0,0,0}, aH1 = {0,0,0,0};
    for (int e = start; e < end; e += 8) {
        const int4* q = reinterpret_cast<const int4*>(cv + e);
        int4 a = q[0], b = q[1], c = q[2], d = q[3];
        uint4 u0 = *reinterpret_cast<const uint4*>(Zg + (((size_t)a.x) << 11) + col0);
        uint4 u1 = *reinterpret_cast<const uint4*>(Zg + (((size_t)a.z) << 11) + col0);
        uint4 u2 = *reinterpret_cast<const uint4*>(Zg + (((size_t)b.x) << 11) + col0);
        uint4 u3 = *reinterpret_cast<const uint4*>(Zg + (((size_t)b.z) << 11) + col0);
        uint4 u4 = *reinterpret_cast<const uint4*>(Zg + (((size_t)c.x) << 11) + col0);
        uint4 u5 = *reinterpret_cast<const uint4*>(Zg + (((size_t)c.z) << 11) + col0);
        uint4 u6 = *reinterpret_cast<const uint4*>(Zg + (((size_t)d.x) << 11) + col0);
        uint4 u7 = *reinterpret_cast<const uint4*>(Zg + (((size_t)d.z) << 11) + col0);
        f4 lo, hi;
        up8(u0, lo, hi); aL0 += __int_as_float(a.y) * lo; aH0 += __int_as_float(a.y) * hi;
        up8(u1, lo, hi); aL1 += __int_as_float(a.w) * lo; aH1 += __int_as_float(a.w) * hi;
        up8(u2, lo, hi); aL0 += __int_as_float(b.y) * lo; aH0 += __int_as_float(b.y) * hi;
        up8(u3, lo, hi); aL1 += __int_as_float(b.w) * lo; aH1 += __int_as_float(b.w) * hi;
        up8(u4, lo, hi); aL0 += __int_as_float(c.y) * lo; aH0 += __int_as_float(c.y) * hi;
        up8(u5, lo, hi); aL1 += __int_as_float(c.w) * lo; aH1 += __int_as_float(c.w) * hi;
        up8(u6, lo, hi); aL0 += __int_as_float(d.y) * lo; aH0 += __int_as_float(d.y) * hi;
        up8(u7, lo, hi); aL1 += __int_as_float(d.w) * lo; aH1 += __int_as_float(d.w) * hi;
    }
    size_t o = (((size_t)n) << 11) + col0;
    f4 tL = aL0 + aL1, tH = aH0 + aH1;
    if (Pown) {
        uint4 pu = *reinterpret_cast<const uint4*>(Pown + o);
        f4 pL, pH;
        up8(pu, pL, pH);
        tL = 2.f * tL - pL;
        tH = 2.f * tH - pH;
    }
    uint4 st;
    st.x = bfpk(tL.x, tL.y); st.y = bfpk(tL.z, tL.w);
    st.z = bfpk(tH.x, tH.y); st.w = bfpk(tH.z, tH.w);
    *reinterpret_cast<uint4*>(Tout + o) = st;
}

// ---------------------------------------------------------------------------
// Chebyshev finalizer, register-direct MFMA (no LDS):
// Lane map col0 = chunk*512 + (lane&15)*32 + (lane>>4)*8 -> each lane's own-row
// loads and gather accumulator ARE the MFMA A-fragments (lane = row lane&15,
// k-group lane>>4). Wb holds B-fragments pre-packed (k_packw). Validated C/D
// mapping: co = lane&15 (+16 for accB), batch = (lane>>4)*4 + reg.
// COUT=32: bf16 out [N][2048]; COUT=4: fp32 out [N][256] (B cols 4..15 zero).
// ---------------------------------------------------------------------------
template <int COUT>
__global__ __launch_bounds__(256) void k_cheb_mfma(
    const int* __restrict__ rowptr, const int2* __restrict__ cv,
    const ushort_t* __restrict__ T2g,  // gather source (T2), also own-row read
    const ushort_t* __restrict__ T1,   // own-row: Pown + W1 operand
    const ushort_t* __restrict__ H,    // own-row: W0 operand
    const uint_t* __restrict__ Wb,     // [4][32co][16] bf16-pair fragments
    const float* __restrict__ bias,    // [COUT]
    void* __restrict__ OUTv)
{
    int chunk = blockIdx.x & 3;
    int rowblk = blockIdx.x >> 2;
    int wave = threadIdx.x >> 6;
    int lane = threadIdx.x & 63;
    int n = rowblk * 4 + wave;
    int b16 = lane & 15, qk = lane >> 4;
    int col0 = chunk * 512 + b16 * 32 + qk * 8;

    int start = rowptr[n], end = rowptr[n + 1];
    f4 aL0 = {0,0,0,0}, aH0 = {0,0,0,0}, aL1 = {0,0,0,0}, aH1 = {0,0,0,0};
    for (int e = start; e < end; e += 8) {
        const int4* q = reinterpret_cast<const int4*>(cv + e);
        int4 a = q[0], b = q[1], c = q[2], d = q[3];
        uint4 u0 = *reinterpret_cast<const uint4*>(T2g + (((size_t)a.x) << 11) + col0);
        uint4 u1 = *reinterpret_cast<const uint4*>(T2g + (((size_t)a.z) << 11) + col0);
        uint4 u2 = *reinterpret_cast<const uint4*>(T2g + (((size_t)b.x) << 11) + col0);
        uint4 u3 = *reinterpret_cast<const uint4*>(T2g + (((size_t)b.z) << 11) + col0);
        uint4 u4 = *reinterpret_cast<const uint4*>(T2g + (((size_t)c.x) << 11) + col0);
        uint4 u5 = *reinterpret_cast<const uint4*>(T2g + (((size_t)c.z) << 11) + col0);
        uint4 u6 = *reinterpret_cast<const uint4*>(T2g + (((size_t)d.x) << 11) + col0);
        uint4 u7 = *reinterpret_cast<const uint4*>(T2g + (((size_t)d.z) << 11) + col0);
        f4 lo, hi;
        up8(u0, lo, hi); aL0 += __int_as_float(a.y) * lo; aH0 += __int_as_float(a.y) * hi;
        up8(u1, lo, hi); aL1 += __int_as_float(a.w) * lo; aH1 += __int_as_float(a.w) * hi;
        up8(u2, lo, hi); aL0 += __int_as_float(b.y) * lo; aH0 += __int_as_float(b.y) * hi;
        up8(u3, lo, hi); aL1 += __int_as_float(b.w) * lo; aH1 += __int_as_float(b.w) * hi;
        up8(u4, lo, hi); aL0 += __int_as_float(c.y) * lo; aH0 += __int_as_float(c.y) * hi;
        up8(u5, lo, hi); aL1 += __int_as_float(c.w) * lo; aH1 += __int_as_float(c.w) * hi;
        up8(u6, lo, hi); aL0 += __int_as_float(d.y) * lo; aH0 += __int_as_float(d.y) * hi;
        up8(u7, lo, hi); aL1 += __int_as_float(d.w) * lo; aH1 += __int_as_float(d.w) * hi;
    }
    size_t o = (((size_t)n) << 11) + col0;

    // A-fragments directly in registers: planes {H, T1, T2, T3}
    uint4 a1 = *reinterpret_cast<const uint4*>(T1 + o);
    uint4 a3;
    {
        f4 pL, pH;
        up8(a1, pL, pH);
        f4 tL = 2.f * (aL0 + aL1) - pL;
        f4 tH = 2.f * (aH0 + aH1) - pH;
        a3.x = bfpk(tL.x, tL.y); a3.y = bfpk(tL.z, tL.w);
        a3.z = bfpk(tH.x, tH.y); a3.w = bfpk(tH.z, tH.w);
    }
    uint4 a2 = *reinterpret_cast<const uint4*>(T2g + o);
    uint4 a0 = *reinterpret_cast<const uint4*>(H + o);

    // B-fragments from pre-packed global (L2-hot, 8KB)
    const uint_t* wb = Wb + b16 * 16 + qk * 4;
    f4 accA = {0,0,0,0}, accB = {0,0,0,0};
#pragma unroll
    for (int kk = 0; kk < 4; ++kk) {
        uint4 af4 = (kk == 0) ? a0 : (kk == 1) ? a1 : (kk == 2) ? a2 : a3;
        bf16x8 af = *reinterpret_cast<bf16x8*>(&af4);
        uint4 w0 = *reinterpret_cast<const uint4*>(wb + kk * 512);
        bf16x8 bf0 = *reinterpret_cast<bf16x8*>(&w0);
        accA = __builtin_amdgcn_mfma_f32_16x16x32_bf16(af, bf0, accA, 0, 0, 0);
        if constexpr (COUT == 32) {
            uint4 w1 = *reinterpret_cast<const uint4*>(wb + kk * 512 + 256);
            bf16x8 bf1_ = *reinterpret_cast<bf16x8*>(&w1);
            accB = __builtin_amdgcn_mfma_f32_16x16x32_bf16(af, bf1_, accB, 0, 0, 0);
        }
    }

    int co = lane & 15;
    if constexpr (COUT == 32) {
        float bA = bias[co], bB = bias[co + 16];
        ushort_t* OB = (ushort_t*)OUTv;
        size_t obase = (((size_t)n) << 11) + chunk * 512;
#pragma unroll
        for (int r = 0; r < 4; ++r) {
            int gb = qk * 4 + r;
            float vA = accA[r] + bA;
            float vB = accB[r] + bB;
            vA = vA > 0.f ? vA : 0.f;
            vB = vB > 0.f ? vB : 0.f;
            OB[obase + gb * 32 + co]      = bf1(vA);
            OB[obase + gb * 32 + co + 16] = bf1(vB);
        }
    } else {  // COUT == 4: fp32 out [N][256], only co<4 valid
        if (co < 4) {
            float bA = bias[co];
            float* OF = (float*)OUTv;
            size_t obase = (size_t)n * 256 + chunk * 64;
#pragma unroll
            for (int r = 0; r < 4; ++r) {
                int gb = qk * 4 + r;
                float vA = accA[r] + bA;
                vA = vA > 0.f ? vA : 0.f;
                OF[obase + gb * 4 + co] = vA;
            }
        }
    }
}

// ---------------------------------------------------------------------------
// FC1: split-K over 128 blocks, atomic accumulate. h[b, n*4+c] = H5[n, b*4+c]
// ---------------------------------------------------------------------------
__global__ __launch_bounds__(256) void k_fc1(const float* __restrict__ H5,
                                             const float* __restrict__ fw1,
                                             float* __restrict__ fc1out) {
    __shared__ float hT[128 * 65];
    __shared__ float wS[32 * 128];
    int tid = threadIdx.x;
    int n0 = blockIdx.x * 32;
    for (int idx = tid; idx < 8192; idx += 256) {
        int n_l = idx >> 8;
        int rem = idx & 255;
        int b = rem >> 2, c = rem & 3;
        int kk = n_l * 4 + c;
        hT[kk * 65 + b] = H5[(size_t)(n0 + n_l) * 256 + rem];
    }
    float acc[8][4];
#pragma unroll
    for (int i = 0; i < 8; ++i)
#pragma unroll
        for (int j = 0; j < 4; ++j) acc[i][j] = 0.f;
    int bq = tid >> 5;
    int jq = tid & 31;
    for (int kb = 0; kb < 128; kb += 32) {
        __syncthreads();
        for (int idx = tid; idx < 4096; idx += 256) {
            int kl = idx >> 7, j = idx & 127;
            wS[idx] = fw1[(size_t)(n0 * 4 + kb + kl) * 128 + j];
        }
        __syncthreads();
        for (int kl = 0; kl < 32; ++kl) {
            int kk = kb + kl;
            float4 w = *reinterpret_cast<const float4*>(&wS[kl * 128 + jq * 4]);
#pragma unroll
            for (int bi = 0; bi < 8; ++bi) {
                float h = hT[kk * 65 + bq * 8 + bi];
                acc[bi][0] += h * w.x;
                acc[bi][1] += h * w.y;
                acc[bi][2] += h * w.z;
                acc[bi][3] += h * w.w;
            }
        }
    }
#pragma unroll
    for (int bi = 0; bi < 8; ++bi)
#pragma unroll
        for (int ji = 0; ji < 4; ++ji)
            atomicAdd(&fc1out[(bq * 8 + bi) * 128 + jq * 4 + ji], acc[bi][ji]);
}

__global__ __launch_bounds__(128) void k_fc23(const float* __restrict__ fc1out,
                                              const float* __restrict__ fb1,
                                              const float* __restrict__ fw2,
                                              const float* __restrict__ fb2,
                                              const float* __restrict__ fw3,
                                              const float* __restrict__ fb3,
                                              float* __restrict__ out) {
    int b = blockIdx.x;
    int j = threadIdx.x;
    __shared__ float r[128];
    __shared__ float s1[128];
    r[j] = fc1out[b * 128 + j] + fb1[j];
    __syncthreads();
    float acc = fb2[j];
    for (int i = 0; i < 128; ++i) acc += r[i] * fw2[i * 128 + j];
    s1[j] = acc;
    __syncthreads();
    if (j < 9) {
        float a2 = fb3[j];
        for (int i = 0; i < 128; ++i) a2 += s1[i] * fw3[i * 9 + j];
        out[b * 9 + j] = a2;
    }
}

// ---------------------------------------------------------------------------
extern "C" void kernel_launch(void* const* d_in, const int* in_sizes, int n_in,
                              void* d_out, int out_size, void* d_ws, size_t ws_size,
                              hipStream_t stream) {
    const float* x   = (const float*)d_in[0];
    const int*   src = (const int*)d_in[1];
    const int*   dst = (const int*)d_in[2];
    const float* ew  = (const float*)d_in[3];
    const float* w1  = (const float*)d_in[4];
    const float* b1  = (const float*)d_in[5];
    const float* w2  = (const float*)d_in[6];
    const float* b2  = (const float*)d_in[7];
    const float* w3  = (const float*)d_in[8];
    const float* b3  = (const float*)d_in[9];
    const float* w4  = (const float*)d_in[10];
    const float* b4  = (const float*)d_in[11];
    const float* w5  = (const float*)d_in[12];
    const float* b5  = (const float*)d_in[13];
    const float* fw1 = (const float*)d_in[14];
    const float* fb1 = (const float*)d_in[15];
    const float* fw2 = (const float*)d_in[16];
    const float* fb2 = (const float*)d_in[17];
    const float* fw3 = (const float*)d_in[18];
    const float* fb3 = (const float*)d_in[19];
    float* out = (float*)d_out;

    char* p = (char*)d_ws;
    const size_t XBYTES = (size_t)NN * 2048 * 2;  // 16 MB (bf16)
    ushort_t* X0 = (ushort_t*)(p + 0 * XBYTES);
    ushort_t* X1 = (ushort_t*)(p + 1 * XBYTES);
    ushort_t* X2 = (ushort_t*)(p + 2 * XBYTES);
    ushort_t* X3 = (ushort_t*)(p + 3 * XBYTES);
    size_t off = 4 * XBYTES;
    float* H5     = (float*)(p + off); off += (size_t)NN * 256 * 4;  // fp32
    float* deg    = (float*)(p + off); off += (size_t)NN * 4;
    int*   cnt    = (int*)(p + off);   off += (size_t)NN * 4;
    int*   cursor = (int*)(p + off);   off += (size_t)NN * 4;
    int*   rowptr = (int*)(p + off);   off += (size_t)(NN + 4) * 4;
    int2*  cv     = (int2*)(p + off);  off += (size_t)EPAD * 8;
    float* fc1o   = (float*)(p + off); off += (size_t)BB * 128 * 4;
    float* xn0    = (float*)(p + off); off += (size_t)NN * 64 * 4;
    float* tn1    = (float*)(p + off); off += (size_t)NN * 64 * 4;
    float* tn2    = (float*)(p + off); off += (size_t)NN * 64 * 4;
    float* tn3    = (float*)(p + off); off += (size_t)NN * 64 * 4;
    uint_t* Wb    = (uint_t*)(p + off); off += (size_t)4 * 2048 * 4;
    if (off > ws_size) return;

    hipMemsetAsync(deg, 0, NN * 4, stream);
    hipMemsetAsync(cnt, 0, NN * 4, stream);
    hipMemsetAsync(cv, 0, (size_t)EPAD * 8, stream);
    hipMemsetAsync(fc1o, 0, BB * 128 * 4, stream);

    k_deg_hist<<<EE / 256, 256, 0, stream>>>(src, dst, ew, deg, cnt);
    k_scan<<<1, 1024, 0, stream>>>(cnt, rowptr, cursor);
    k_fill<<<EE / 256, 256, 0, stream>>>(src, dst, ew, deg, cursor, cv);
    k_packw<<<32, 256, 0, stream>>>(w2, w3, w4, w5, Wb);
    k_transpose_x<<<NN / 64, 256, 0, stream>>>(x, xn0);

    // ------------------- layer 1 entirely narrow fp32, then one bf16 expand
    k_spmm_narrow<<<NN, 64, 0, stream>>>(rowptr, cv, xn0, nullptr, tn1, 1.f, 0);
    k_spmm_narrow<<<NN, 64, 0, stream>>>(rowptr, cv, tn1, xn0, tn2, 2.f, 1);
    k_spmm_narrow<<<NN, 64, 0, stream>>>(rowptr, cv, tn2, tn1, tn3, 2.f, 1);
    k_expand1<<<NN, 256, 0, stream>>>(xn0, tn1, tn2, tn3, w1, b1, X3);  // H1 -> X3

    const int GRID4 = (NN / 4) * 4;   // 4096 blocks: 4 chunks x 512 cols
    // ------------------- layers 2-4: S1, S2 pure; S3 fused MFMA finalizer
    auto run32 = [&](const ushort_t* H, ushort_t* T1, ushort_t* T2, ushort_t* OUT,
                     const uint_t* WbL, const float* B) {
        k_spmm_pure<<<GRID4, 256, 0, stream>>>(rowptr, cv, H, nullptr, T1);
        k_spmm_pure<<<GRID4, 256, 0, stream>>>(rowptr, cv, T1, H, T2);
        k_cheb_mfma<32><<<GRID4, 256, 0, stream>>>(rowptr, cv, T2, T1, H, WbL, B, OUT);
    };
    run32(X3, X0, X1, X2, Wb + 0 * 2048, b2);
    run32(X2, X3, X0, X1, Wb + 1 * 2048, b3);
    run32(X1, X2, X3, X0, Wb + 2 * 2048, b4);

    // ------------------- layer 5 (COUT=4): H=X0 -> H5 fp32 [N][256]
    k_spmm_pure<<<GRID4, 256, 0, stream>>>(rowptr, cv, X0, nullptr, X1);
    k_spmm_pure<<<GRID4, 256, 0, stream>>>(rowptr, cv, X1, X0, X2);
    k_cheb_mfma<4><<<GRID4, 256, 0, stream>>>(rowptr, cv, X2, X1, X0, Wb + 3 * 2048, b5, H5);

    // ------------------- FC head
    k_fc1<<<128, 256, 0, stream>>>(H5, fw1, fc1o);
    k_fc23<<<BB, 128, 0, stream>>>(fc1o, fb1, fw2, fb2, fw3, fb3, out);
}